// Round 3
// baseline (8440.419 us; speedup 1.0000x reference)
//
#include <hip/hip_runtime.h>
#include <stdint.h>

typedef short short8 __attribute__((ext_vector_type(8)));
typedef short short4v __attribute__((ext_vector_type(4)));
typedef float floatx4 __attribute__((ext_vector_type(4)));

#define LOG2E 1.44269504088896340736f

__device__ __forceinline__ float bf2f(unsigned short u) {
  unsigned v = ((unsigned)u) << 16;
  return __builtin_bit_cast(float, v);
}
__device__ __forceinline__ unsigned short f2bf(float f) {
  unsigned v = __builtin_bit_cast(unsigned, f);
  v += 0x7FFFu + ((v >> 16) & 1u);   // RNE
  return (unsigned short)(v >> 16);
}
__device__ __forceinline__ float fast_exp2(float x) {
#if __has_builtin(__builtin_amdgcn_exp2f)
  return __builtin_amdgcn_exp2f(x);
#else
  return exp2f(x);
#endif
}
__device__ __forceinline__ float fast_rcp(float x) {
#if __has_builtin(__builtin_amdgcn_rcpf)
  return __builtin_amdgcn_rcpf(x);
#else
  return 1.0f / x;
#endif
}
__device__ __forceinline__ float fsig(float x) {
  return fast_rcp(1.0f + fast_exp2(-LOG2E * x));
}
__device__ __forceinline__ floatx4 mfma16(short8 a, short8 b, floatx4 c) {
  return __builtin_amdgcn_mfma_f32_16x16x32_bf16(a, b, c, 0, 0, 0);
}

// ---------------------------------------------------------------------------
// Dtype detection: f32 buffers show even-u16 "exponent" >= 0xF0 often; bf16
// 0.05-scaled weights never do. flag: 1 = f32, 0 = bf16.
// ---------------------------------------------------------------------------
__global__ __launch_bounds__(256) void detect_kernel(
    const unsigned short* __restrict__ w, int n_u16, int* __restrict__ flag)
{
  __shared__ int cnt;
  if (threadIdx.x == 0) cnt = 0;
  __syncthreads();
  int local = 0;
  for (int i = threadIdx.x * 2; i < n_u16; i += 512) {
    unsigned e = (w[i] >> 7) & 0xFF;
    if (e >= 0xF0) local++;
  }
  atomicAdd(&cnt, local);
  __syncthreads();
  if (threadIdx.x == 0) *flag = (cnt > 64) ? 1 : 0;
}

// ---------------------------------------------------------------------------
// One merged kernel canonicalizing all 14 weight tensors to bf16 in ws.
// Gate-block pre-scaling: i/f/o rows (and biases) scaled by log2(e), g rows
// by 2*log2(e) -> recurrence needs only bare exp2; cell state carried in the
// 2*log2(e)*c domain. fc weights (12,13) stay unscaled.
// ---------------------------------------------------------------------------
__global__ __launch_bounds__(256) void convertw_kernel(
    const void* s0, const void* s1, const void* s2, const void* s3,
    const void* s4, const void* s5, const void* s6, const void* s7,
    const void* s8, const void* s9, const void* s10, const void* s11,
    const void* s12, const void* s13,
    unsigned short* __restrict__ wbuf, const int* __restrict__ flag)
{
  const void* srcs[14] = {s0, s1, s2, s3, s4, s5, s6, s7, s8, s9, s10, s11, s12, s13};
  const int woff[14] = {0,      49152,  114688, 115200, 164352, 229888,
                        230400, 361472, 427008, 427520, 558592, 624128,
                        624640, 624896};
  const int wlen[14] = {49152, 65536, 512, 49152, 65536, 512,
                        131072, 65536, 512, 131072, 65536, 512, 256, 1};
  const int glen[14] = {96 * 128, 128 * 128, 128, 96 * 128, 128 * 128, 128,
                        256 * 128, 128 * 128, 128, 256 * 128, 128 * 128, 128,
                        0, 0};
  int sb = 0, i = 0;
  for (i = 0; i < 14; ++i) {
    int nb = (wlen[i] + 1023) >> 10;
    if ((int)blockIdx.x < sb + nb) break;
    sb += nb;
  }
  const int base = ((int)blockIdx.x - sb) * 1024 + (int)threadIdx.x * 4;
  unsigned short* dst = wbuf + woff[i];
  const int f32 = *flag;
  const int gl = glen[i];
#pragma unroll
  for (int j = 0; j < 4; ++j) {
    const int idx = base + j;
    if (idx >= wlen[i]) break;
    float v = f32 ? ((const float*)srcs[i])[idx]
                  : bf2f(((const unsigned short*)srcs[i])[idx]);
    if (gl) {
      const int gate = (int)((unsigned)idx / (unsigned)gl);  // row >> 7
      v *= (gate == 2) ? (2.0f * LOG2E) : LOG2E;
    }
    dst[idx] = f2bf(v);
  }
}

// ---------------------------------------------------------------------------
// GEMM body for 512-thread blocks: all 8 waves stage A into LDS, then all 8
// compute 512 cols (8 waves x 64). Z output bf16, BG-MAJOR
// [t][dir][bg][512 cols][16 b]. (Weights pre-scaled.)
// ---------------------------------------------------------------------------
template <int K>
__device__ __forceinline__ void gemm512_body(
    unsigned short* As, int t, int slice,
    const void* __restrict__ A, size_t a_off, int dyn,
    const int* __restrict__ flag,
    const unsigned short* __restrict__ Bf, const unsigned short* __restrict__ Bb,
    const unsigned short* __restrict__ biasf, const unsigned short* __restrict__ biasb,
    unsigned short* __restrict__ Z)
{
  constexpr int RS = K + 8;
  const int tid = threadIdx.x, lane = tid & 63;
  const int q = lane >> 4, cc = lane & 15;
  constexpr int K8 = K / 8;
  const int use32 = dyn ? *flag : 0;   // wave-uniform
  if (use32) {
    const float* Arow = (const float*)A + a_off + (size_t)t * 64 * K;
    for (int ci = tid; ci < 64 * K8; ci += 512) {
      int r_ = ci / K8, c8 = ci % K8;
      const float* p = Arow + r_ * K + c8 * 8;
      floatx4 x0 = *(const floatx4*)p;
      floatx4 x1 = *(const floatx4*)(p + 4);
      short8 s;
#pragma unroll
      for (int j = 0; j < 4; ++j) {
        s[j] = (short)f2bf(x0[j]);
        s[4 + j] = (short)f2bf(x1[j]);
      }
      *(short8*)&As[r_ * RS + c8 * 8] = s;
    }
  } else {
    const unsigned short* Arow = (const unsigned short*)A + a_off + (size_t)t * 64 * K;
    for (int ci = tid; ci < 64 * K8; ci += 512) {
      int r_ = ci / K8, c8 = ci % K8;
      *(short8*)&As[r_ * RS + c8 * 8] = *(const short8*)&Arow[r_ * K + c8 * 8];
    }
  }
  __syncthreads();
  const int w = tid >> 6;
  const unsigned short* Bp    = slice ? Bb : Bf;
  const unsigned short* biasp = slice ? biasb : biasf;
  const int cb = w * 64;
  const int dslab = slice * 4;
  floatx4 acc[4][4];
#pragma unroll
  for (int m = 0; m < 4; ++m)
#pragma unroll
    for (int n = 0; n < 4; ++n)
#pragma unroll
      for (int r = 0; r < 4; ++r) acc[m][n][r] = 0.f;
#pragma unroll
  for (int ks = 0; ks < K / 32; ++ks) {
    short8 af[4], bfr[4];
#pragma unroll
    for (int m = 0; m < 4; ++m)
      af[m] = *(const short8*)&As[(m * 16 + cc) * RS + ks * 32 + q * 8];
#pragma unroll
    for (int n = 0; n < 4; ++n)
      bfr[n] = *(const short8*)&Bp[(size_t)(cb + n * 16 + cc) * K + ks * 32 + q * 8];
#pragma unroll
    for (int m = 0; m < 4; ++m)
#pragma unroll
      for (int n = 0; n < 4; ++n)
        acc[m][n] = mfma16(af[m], bfr[n], acc[m][n]);
  }
#pragma unroll
  for (int n = 0; n < 4; ++n) {
    const int col = cb + n * 16 + cc;
    const float bv = bf2f(biasp[col]);
#pragma unroll
    for (int m = 0; m < 4; ++m) {
      short4v zv;
#pragma unroll
      for (int r = 0; r < 4; ++r)
        zv[r] = (short)f2bf(acc[m][n][r] + bv);
      *(short4v*)&Z[((size_t)t * 8 + dslab + m) * 8192 + col * 16 + q * 4] = zv;
    }
  }
}

// ---------------------------------------------------------------------------
// FC body (512 threads): block idx covers timesteps idx*2 and idx*2+1.
// ---------------------------------------------------------------------------
__device__ __forceinline__ void fc512_body(
    int idx, int steps, const unsigned short* __restrict__ ys1,
    const unsigned short* __restrict__ fcw, const unsigned short* __restrict__ fcb,
    void* __restrict__ out, size_t out_off, const int* __restrict__ flag)
{
  const int tid = threadIdx.x;
  const int w = tid >> 6, lane = tid & 63;
  const int t = idx * 2 + (w >> 2);
  if (t >= steps) return;
  const int w4 = w & 3;
  const int o = lane & 15, q = lane >> 4;
  const int b = w4 * 16 + o;
  const unsigned short* rp = ys1 + ((size_t)t * 64 + b) * 256 + q * 64;
  float s = 0.f;
#pragma unroll
  for (int j = 0; j < 16; ++j) {
    short4v v = *(const short4v*)(rp + j * 4);
    const unsigned short* wp = fcw + q * 64 + j * 4;
#pragma unroll
    for (int k = 0; k < 4; ++k) s += bf2f((unsigned short)v[k]) * bf2f(wp[k]);
  }
  s += __shfl_xor(s, 16, 64);
  s += __shfl_xor(s, 32, 64);
  if (q == 0) {
    const float v = fsig(s + bf2f(fcb[0]));
    const size_t oidx = out_off + (size_t)t * 64 + b;
    if (*flag) ((float*)out)[oidx] = v;
    else       ((unsigned short*)out)[oidx] = f2bf(v);
  }
}

// ---------------------------------------------------------------------------
// Fused pipeline kernel, 512-thread blocks (8 waves).
// Blocks 0..7: MERGED recurrence - each block runs BOTH the L0 (ctx a) and
// L1 (ctx b) chains for its (d,bg) slice between the same barriers. The two
// chains are independent, so the scheduler interleaves a's trans-latency-
// bound pointwise with b's MFMA/DS work and vice versa, filling the
// dependency bubbles that pinned the round-2 period at ~2120 cyc/step with
// only 2 lockstep waves/SIMD. One barrier per merged step (was 2). Register
// cost: 2x bfrag (~128) + 2x acc/af (~64) -> ~240 VGPR = exactly 2
// waves/SIMD, which also makes rec CUs hardware-exclusive again.
// Z prefetch: per ctx, TWO named register sets (A/B), 2x-unrolled loop ->
// vmcnt wait lands two merged periods after issue.
// Blocks 8+: g96(c+1), g256(c-1), fc(c-3) workers (parity-disjoint buffers).
// ---------------------------------------------------------------------------
__global__ __attribute__((amdgpu_waves_per_eu(2, 4))) __launch_bounds__(512)
void rec_kernel(
    const unsigned short* __restrict__ Za, const unsigned short* __restrict__ whhfa,
    const unsigned short* __restrict__ whhba,
    unsigned short* __restrict__ ysa, float* __restrict__ ca,
    unsigned short* __restrict__ ha, int inita, int acta,
    const unsigned short* __restrict__ Zb, const unsigned short* __restrict__ whhfb,
    const unsigned short* __restrict__ whhbb,
    unsigned short* __restrict__ ysb, float* __restrict__ cb_,
    unsigned short* __restrict__ hb, int initb, int actb,
    int steps,
    const void* __restrict__ x, size_t x_off, int do96, const int* __restrict__ flag,
    const unsigned short* __restrict__ wih0f, const unsigned short* __restrict__ wih0b,
    const unsigned short* __restrict__ b0f, const unsigned short* __restrict__ b0b,
    unsigned short* __restrict__ Z0n,
    const unsigned short* __restrict__ ys0g, int do256,
    const unsigned short* __restrict__ wih1f, const unsigned short* __restrict__ wih1b,
    const unsigned short* __restrict__ b1f, const unsigned short* __restrict__ b1b,
    unsigned short* __restrict__ Z1n,
    const unsigned short* __restrict__ fcsrc,
    const unsigned short* __restrict__ fcw, const unsigned short* __restrict__ fcb,
    void* __restrict__ out, size_t fc_off, int fcn)
{
  __shared__ __align__(16) unsigned char smem[34816];
  const int bx = blockIdx.x;
  const int g96n = steps * 2;

  if (bx >= 8) {
    const int wi = bx - 8;
    if (wi < g96n) {                       // g96 (next chunk L0)
      if (!do96) return;
      gemm512_body<96>((unsigned short*)smem, wi >> 1, wi & 1, x, x_off, 1,
                       flag, wih0f, wih0b, b0f, b0b, Z0n);
    } else if (wi < 2 * g96n) {            // g256 (L1 chunk c-1)
      if (!do256) return;
      const int idx = wi - g96n;
      gemm512_body<256>((unsigned short*)smem, idx >> 1, idx & 1, ys0g, 0, 0,
                        flag, wih1f, wih1b, b1f, b1b, Z1n);
    } else {                               // fc (chunk c-3)
      if (fcn <= 0) return;
      fc512_body(wi - 2 * g96n, steps, fcsrc, fcw, fcb, out, fc_off, flag);
    }
    return;
  }

  // ---- merged recurrence path (both ctx on one CU) ----
  if (!acta && !actb) return;
  const int tid = threadIdx.x;
  const int d = (bx >> 2) & 1, bg = bx & 3;

  unsigned short (*hbA)[16][136] = (unsigned short(*)[16][136])smem;
  unsigned short (*hbB)[16][136] = (unsigned short(*)[16][136])(smem + 8704);

  const int w = tid >> 6, lane = tid & 63, q = lane >> 4, cc = lane & 15;
  const int u = w * 16 + cc;
  const int row = tid >> 5;          // 0..15 (32 threads per row)
  const int col4 = (tid & 31) * 4;   // 0..124

  const unsigned short* Zc[2]   = {Za, Zb};
  const unsigned short* whhc[2] = {d ? whhba : whhfa, d ? whhbb : whhfb};
  float* cstc[2]                = {ca, cb_};
  unsigned short* hstc[2]       = {ha, hb};
  unsigned short* ysc[2]        = {ysa, ysb};
  const int initc[2]            = {inita, initb};
  const int actc[2]             = {acta, actb};

  short8 bfrag[2][4][4];
  float creg[2][4];                  // cell state, carried as 2*log2(e)*c
  short4v zA[2][4], zB[2][4];
  const unsigned short* zpA[2];
  const unsigned short* zpB[2];
  unsigned short* ysp[2];

#pragma unroll
  for (int i = 0; i < 2; ++i) {
    if (!actc[i]) continue;
    const unsigned short* whh = whhc[i];
#pragma unroll
    for (int g = 0; g < 4; ++g)
#pragma unroll
      for (int k = 0; k < 4; ++k)
        bfrag[i][g][k] =
            *(const short8*)(whh + (size_t)(g * 128 + u) * 128 + k * 32 + q * 8);
    unsigned short (*hb_)[16][136] = i ? hbB : hbA;
    if (initc[i]) {
#pragma unroll
      for (int r = 0; r < 4; ++r) creg[i][r] = 0.f;
      short4v zz = {0, 0, 0, 0};
      *(short4v*)&hb_[0][row][col4] = zz;
    } else {
#pragma unroll
      for (int r = 0; r < 4; ++r)
        creg[i][r] = cstc[i][(size_t)(d * 64 + bg * 16 + q * 4 + r) * 128 + u];
      *(short4v*)&hb_[0][row][col4] =
          *(const short4v*)(hstc[i] + (size_t)(d * 64 + bg * 16 + row) * 128 + col4);
    }
    const size_t zbase = (size_t)(d * 4 + bg) * 8192 + u * 16 + q * 4;
    zpA[i] = Zc[i] + zbase;            // even-step addresses
    zpB[i] = Zc[i] + zbase + 65536;    // odd-step addresses
#pragma unroll
    for (int g = 0; g < 4; ++g) zA[i][g] = *(const short4v*)(zpA[i] + g * 2048);
#pragma unroll
    for (int g = 0; g < 4; ++g) zB[i][g] = *(const short4v*)(zpB[i] + g * 2048);
    zpA[i] += 131072;
    zpB[i] += 131072;
    ysp[i] = ysc[i] + (size_t)(bg * 16 + row) * 256 + d * 128 + col4;
  }
  __syncthreads();

  // --- per-ctx helpers (i passed as literal -> fully constant-folded) ---
  auto gstep = [&](int i, short4v (&zs)[4], const unsigned short*& zp,
                   floatx4 (&acc)[4], int cur) __attribute__((always_inline)) {
    unsigned short (*hb_)[16][136] = i ? hbB : hbA;
#pragma unroll
    for (int g = 0; g < 4; ++g)
#pragma unroll
      for (int r = 0; r < 4; ++r)
        acc[g][r] = bf2f((unsigned short)zs[g][r]);
    // prefetch this set's t+2 data; vmcnt wait is two merged periods away
#pragma unroll
    for (int g = 0; g < 4; ++g) zs[g] = *(const short4v*)(zp + g * 2048);
    zp += 131072;
    short8 af[4];
#pragma unroll
    for (int k = 0; k < 4; ++k)
      af[k] = *(const short8*)&hb_[cur][cc][k * 32 + q * 8];
#pragma unroll
    for (int g = 0; g < 4; ++g)
#pragma unroll
      for (int k = 0; k < 4; ++k)
        acc[g] = mfma16(af[k], bfrag[i][g][k], acc[g]);
  };

  auto pstep = [&](int i, floatx4 (&acc)[4], int nxt) __attribute__((always_inline)) {
    unsigned short (*hb_)[16][136] = i ? hbB : hbA;
    // fused pointwise, log2-domain weights: 5 exp2 + 2 rcp per (b,u).
#pragma unroll
    for (int r = 0; r < 4; ++r) {
      const float ei = fast_exp2(acc[0][r]);
      const float ef = fast_exp2(acc[1][r]);
      const float eg = fast_exp2(acc[2][r]);
      const float a1 = 1.0f + ei, a2 = 1.0f + eg, a3 = 1.0f + ef;
      const float p12 = a1 * a2;
      const float rD = fast_rcp(p12 * a3);
      const float t2 = __builtin_fmaf(eg, 2.0f * LOG2E, -2.0f * LOG2E); // 2L*(eg-1)
      const float it2 = ei * t2 * (a3 * rD);       // 2L * sig(i)*tanh(g)
      const float sf = ef * (p12 * rD);            // sig(f)
      const float cs = __builtin_fmaf(sf, creg[i][r], it2);
      creg[i][r] = cs;
      const float eo = fast_exp2(acc[3][r]);
      const float ec = fast_exp2(fminf(cs, 88.0f));  // e^{2c}
      const float h = eo * (ec - 1.0f) * fast_rcp((1.0f + eo) * (1.0f + ec));
      hb_[nxt][q * 4 + r][u] = f2bf(h);
    }
  };

  auto ystep = [&](int i, int t, int nxt) __attribute__((always_inline)) {
    unsigned short (*hb_)[16][136] = i ? hbB : hbA;
    short4v hv = *(const short4v*)&hb_[nxt][row][col4];
    *(short4v*)(ysp[i] + (size_t)t * 16384) = hv;
  };

  // merged step: both chains between the same barriers; scheduler interleaves
  auto mstep = [&](short4v (&z0)[4], const unsigned short*& zp0,
                   short4v (&z1)[4], const unsigned short*& zp1,
                   int t, int cur, int nxt) __attribute__((always_inline)) {
    floatx4 acc0[4], acc1[4];
    if (acta) gstep(0, z0, zp0, acc0, cur);
    if (actb) gstep(1, z1, zp1, acc1, cur);
    if (acta) pstep(0, acc0, nxt);
    if (actb) pstep(1, acc1, nxt);
    // LDS-only barrier: drain ds ops; z prefetch (vmcnt) stays in flight
    asm volatile("s_waitcnt lgkmcnt(0)\n\ts_barrier" ::: "memory");
    if (acta) ystep(0, t, nxt);
    if (actb) ystep(1, t, nxt);
  };

  int t = 0;
  for (; t + 2 <= steps; t += 2) {
    mstep(zA[0], zpA[0], zA[1], zpA[1], t, 0, 1);
    mstep(zB[0], zpB[0], zB[1], zpB[1], t + 1, 1, 0);
  }
  if (t < steps)                      // odd-step tail (C=1 fallback only)
    mstep(zA[0], zpA[0], zA[1], zpA[1], t, 0, 1);

#pragma unroll
  for (int i = 0; i < 2; ++i) {
    if (!actc[i]) continue;
    unsigned short (*hb_)[16][136] = i ? hbB : hbA;
#pragma unroll
    for (int r = 0; r < 4; ++r)
      cstc[i][(size_t)(d * 64 + bg * 16 + q * 4 + r) * 128 + u] = creg[i][r];
    const int fin = steps & 1;
    *(short4v*)(hstc[i] + (size_t)(d * 64 + bg * 16 + row) * 128 + col4) =
        *(const short4v*)&hb_[fin][row][col4];
  }
}

// ---------------------------------------------------------------------------
// Standalone gemm96 (chunk 0 prologue). Grid 2C x 512.
// ---------------------------------------------------------------------------
__global__ __attribute__((amdgpu_waves_per_eu(2, 4))) __launch_bounds__(512)
void g96_kernel(
    const void* __restrict__ x, size_t x_off, const int* __restrict__ flag,
    const unsigned short* __restrict__ Bf, const unsigned short* __restrict__ Bb,
    const unsigned short* __restrict__ biasf, const unsigned short* __restrict__ biasb,
    unsigned short* __restrict__ Z)
{
  __shared__ __align__(16) unsigned short As[64 * 104];
  gemm512_body<96>(As, blockIdx.x >> 1, blockIdx.x & 1, x, x_off, 1, flag,
                   Bf, Bb, biasf, biasb, Z);
}

// ---------------------------------------------------------------------------
// Standalone FC (final chunk). One wave per (t,b).
// ---------------------------------------------------------------------------
__global__ __launch_bounds__(256) void fc_kernel(
    const unsigned short* __restrict__ ys,
    const unsigned short* __restrict__ fcw,
    const unsigned short* __restrict__ fcb,
    void* __restrict__ out, size_t out_off, int n,
    const int* __restrict__ flag)
{
  const int gw = (int)((blockIdx.x * 256 + threadIdx.x) >> 6);
  const int lane = threadIdx.x & 63;
  if (gw >= n) return;
  const unsigned short* rp = ys + (size_t)gw * 256 + lane * 4;
  float s = 0.f;
#pragma unroll
  for (int i = 0; i < 4; ++i) s += bf2f(rp[i]) * bf2f(fcw[lane * 4 + i]);
#pragma unroll
  for (int m = 32; m >= 1; m >>= 1) s += __shfl_xor(s, m, 64);
  if (lane == 0) {
    const float v = fsig(s + bf2f(fcb[0]));
    if (*flag) ((float*)out)[out_off + gw] = v;
    else       ((unsigned short*)out)[out_off + gw] = f2bf(v);
  }
}

extern "C" void kernel_launch(void* const* d_in, const int* in_sizes, int n_in,
                              void* d_out, int out_size, void* d_ws, size_t ws_size,
                              hipStream_t stream)
{
  (void)in_sizes; (void)n_in; (void)out_size;
  const int S = 4096;

  int* flag = (int*)d_ws;
  unsigned short* wbuf = (unsigned short*)((char*)d_ws + 256);
  static const int woff[14] = {0,      49152,  114688, 115200, 164352, 229888,
                               230400, 361472, 427008, 427520, 558592, 624128,
                               624640, 624896};
  const size_t wbuf_end = 256 + 1250304;  // bytes

  // Double buffers: Z0/Z1 2*C*131072 B each, ys0/ys1 2*C*32768 each
  // -> C*655360 B.
  int C = 1;
  for (int cand = 128; cand >= 1; cand >>= 1) {
    size_t need = (size_t)cand * 655360 + wbuf_end + 196608;
    if (need <= ws_size) { C = cand; break; }
  }
  unsigned short* base = (unsigned short*)((char*)d_ws + wbuf_end);
  unsigned short* Z0buf[2] = {base, base + (size_t)C * 65536};
  unsigned short* Z1buf[2] = {base + (size_t)2 * C * 65536, base + (size_t)3 * C * 65536};
  unsigned short* ys0buf[2] = {base + (size_t)4 * C * 65536,
                               base + (size_t)4 * C * 65536 + (size_t)C * 16384};
  unsigned short* ys1buf[2] = {base + (size_t)4 * C * 65536 + (size_t)2 * C * 16384,
                               base + (size_t)4 * C * 65536 + (size_t)3 * C * 16384};
  float* c0 = (float*)(base + (size_t)4 * C * 65536 + (size_t)4 * C * 16384);
  float* c1 = c0 + 16384;
  unsigned short* h0 = (unsigned short*)(c1 + 16384);
  unsigned short* h1 = h0 + 16384;

  const unsigned short* wih0f = wbuf + woff[0];
  const unsigned short* whh0f = wbuf + woff[1];
  const unsigned short* b0f   = wbuf + woff[2];
  const unsigned short* wih0b = wbuf + woff[3];
  const unsigned short* whh0b = wbuf + woff[4];
  const unsigned short* b0b   = wbuf + woff[5];
  const unsigned short* wih1f = wbuf + woff[6];
  const unsigned short* whh1f = wbuf + woff[7];
  const unsigned short* b1f   = wbuf + woff[8];
  const unsigned short* wih1b = wbuf + woff[9];
  const unsigned short* whh1b = wbuf + woff[10];
  const unsigned short* b1b   = wbuf + woff[11];
  const unsigned short* fcw   = wbuf + woff[12];
  const unsigned short* fcb   = wbuf + woff[13];

  detect_kernel<<<1, 256, 0, stream>>>((const unsigned short*)d_in[1], 49152, flag);
  convertw_kernel<<<614, 256, 0, stream>>>(
      d_in[1], d_in[2], d_in[3], d_in[4], d_in[5], d_in[6], d_in[7],
      d_in[8], d_in[9], d_in[10], d_in[11], d_in[12], d_in[13], d_in[14],
      wbuf, flag);

  const int nc = S / C;
  // prologue: gemm96 for chunk 0
  g96_kernel<<<C * 2, 512, 0, stream>>>(d_in[0], 0, flag,
                                        wih0f, wih0b, b0f, b0b, Z0buf[0]);

  const int GX = 8 + 4 * C + (C + 1) / 2;
  for (int c = 0; c <= nc + 1; ++c) {
    const int p = c & 1, pn = (c + 1) & 1;  // pn == (c-1)&1 == (c+1)&1
    rec_kernel<<<GX, 512, 0, stream>>>(
        // ctx a: L0 chunk c
        Z0buf[p], whh0f, whh0b, ys0buf[p], c0, h0, (c == 0) ? 1 : 0,
        (c <= nc - 1) ? 1 : 0,
        // ctx b: L1 chunk c-2
        Z1buf[p], whh1f, whh1b, ys1buf[p], c1, h1, (c == 2) ? 1 : 0,
        (c >= 2) ? 1 : 0,
        C,
        // embedded g96: chunk c+1
        d_in[0], (size_t)(c + 1) * C * 6144, (c <= nc - 2) ? 1 : 0, flag,
        wih0f, wih0b, b0f, b0b, Z0buf[pn],
        // embedded g256: chunk c-1 (ys0[(c-1)&1] -> Z1[(c-1)&1])
        ys0buf[pn], (c >= 1 && c <= nc) ? 1 : 0, wih1f, wih1b, b1f, b1b, Z1buf[pn],
        // embedded fc: chunk c-3 (reads ys1[(c-3)&1])
        ys1buf[pn], fcw, fcb, d_out,
        (c >= 3) ? (size_t)(c - 3) * C * 64 : 0, (c >= 3) ? C * 64 : 0);
  }
  // tail fc: chunk nc-1 (written during rec launch nc+1)
  fc_kernel<<<C * 16, 256, 0, stream>>>(ys1buf[(nc - 1) & 1], fcw, fcb, d_out,
                                        (size_t)(nc - 1) * C * 64, C * 64, flag);
}

// Round 4
// 8294.428 us; speedup vs baseline: 1.0176x; 1.0176x over previous
//
#include <hip/hip_runtime.h>
#include <stdint.h>

typedef short short8 __attribute__((ext_vector_type(8)));
typedef short short4v __attribute__((ext_vector_type(4)));
typedef float floatx4 __attribute__((ext_vector_type(4)));

#define LOG2E 1.44269504088896340736f

__device__ __forceinline__ float bf2f(unsigned short u) {
  unsigned v = ((unsigned)u) << 16;
  return __builtin_bit_cast(float, v);
}
__device__ __forceinline__ unsigned short f2bf(float f) {
  unsigned v = __builtin_bit_cast(unsigned, f);
  v += 0x7FFFu + ((v >> 16) & 1u);   // RNE
  return (unsigned short)(v >> 16);
}
__device__ __forceinline__ float fast_exp2(float x) {
#if __has_builtin(__builtin_amdgcn_exp2f)
  return __builtin_amdgcn_exp2f(x);
#else
  return exp2f(x);
#endif
}
__device__ __forceinline__ float fast_rcp(float x) {
#if __has_builtin(__builtin_amdgcn_rcpf)
  return __builtin_amdgcn_rcpf(x);
#else
  return 1.0f / x;
#endif
}
__device__ __forceinline__ float fsig(float x) {
  return fast_rcp(1.0f + fast_exp2(-LOG2E * x));
}
__device__ __forceinline__ floatx4 mfma16(short8 a, short8 b, floatx4 c) {
  return __builtin_amdgcn_mfma_f32_16x16x32_bf16(a, b, c, 0, 0, 0);
}

// ---------------------------------------------------------------------------
// Dtype detection: f32 buffers show even-u16 "exponent" >= 0xF0 often; bf16
// 0.05-scaled weights never do. flag: 1 = f32, 0 = bf16.
// ---------------------------------------------------------------------------
__global__ __launch_bounds__(256) void detect_kernel(
    const unsigned short* __restrict__ w, int n_u16, int* __restrict__ flag)
{
  __shared__ int cnt;
  if (threadIdx.x == 0) cnt = 0;
  __syncthreads();
  int local = 0;
  for (int i = threadIdx.x * 2; i < n_u16; i += 512) {
    unsigned e = (w[i] >> 7) & 0xFF;
    if (e >= 0xF0) local++;
  }
  atomicAdd(&cnt, local);
  __syncthreads();
  if (threadIdx.x == 0) *flag = (cnt > 64) ? 1 : 0;
}

// ---------------------------------------------------------------------------
// One merged kernel canonicalizing all 14 weight tensors to bf16 in ws.
// Gate-block pre-scaling: i/f/o rows (and biases) scaled by log2(e), g rows
// by 2*log2(e) -> recurrence needs only bare exp2; cell state carried in the
// 2*log2(e)*c domain. fc weights (12,13) stay unscaled.
// ---------------------------------------------------------------------------
__global__ __launch_bounds__(256) void convertw_kernel(
    const void* s0, const void* s1, const void* s2, const void* s3,
    const void* s4, const void* s5, const void* s6, const void* s7,
    const void* s8, const void* s9, const void* s10, const void* s11,
    const void* s12, const void* s13,
    unsigned short* __restrict__ wbuf, const int* __restrict__ flag)
{
  const void* srcs[14] = {s0, s1, s2, s3, s4, s5, s6, s7, s8, s9, s10, s11, s12, s13};
  const int woff[14] = {0,      49152,  114688, 115200, 164352, 229888,
                        230400, 361472, 427008, 427520, 558592, 624128,
                        624640, 624896};
  const int wlen[14] = {49152, 65536, 512, 49152, 65536, 512,
                        131072, 65536, 512, 131072, 65536, 512, 256, 1};
  const int glen[14] = {96 * 128, 128 * 128, 128, 96 * 128, 128 * 128, 128,
                        256 * 128, 128 * 128, 128, 256 * 128, 128 * 128, 128,
                        0, 0};
  int sb = 0, i = 0;
  for (i = 0; i < 14; ++i) {
    int nb = (wlen[i] + 1023) >> 10;
    if ((int)blockIdx.x < sb + nb) break;
    sb += nb;
  }
  const int base = ((int)blockIdx.x - sb) * 1024 + (int)threadIdx.x * 4;
  unsigned short* dst = wbuf + woff[i];
  const int f32 = *flag;
  const int gl = glen[i];
#pragma unroll
  for (int j = 0; j < 4; ++j) {
    const int idx = base + j;
    if (idx >= wlen[i]) break;
    float v = f32 ? ((const float*)srcs[i])[idx]
                  : bf2f(((const unsigned short*)srcs[i])[idx]);
    if (gl) {
      const int gate = (int)((unsigned)idx / (unsigned)gl);  // row >> 7
      v *= (gate == 2) ? (2.0f * LOG2E) : LOG2E;
    }
    dst[idx] = f2bf(v);
  }
}

// ---------------------------------------------------------------------------
// GEMM body for 1024-thread blocks: all 16 waves stage A into LDS, waves 0..7
// (tid<512) compute 512 cols (8 waves x 64). Z output bf16, BG-MAJOR
// [t][dir][bg][512 cols][16 b]. (Weights pre-scaled.)
// ---------------------------------------------------------------------------
template <int K>
__device__ __forceinline__ void gemm1024_body(
    unsigned short* As, int t, int slice,
    const void* __restrict__ A, size_t a_off, int dyn,
    const int* __restrict__ flag,
    const unsigned short* __restrict__ Bf, const unsigned short* __restrict__ Bb,
    const unsigned short* __restrict__ biasf, const unsigned short* __restrict__ biasb,
    unsigned short* __restrict__ Z)
{
  constexpr int RS = K + 8;
  const int tid = threadIdx.x, lane = tid & 63;
  const int q = lane >> 4, cc = lane & 15;
  constexpr int K8 = K / 8;
  const int use32 = dyn ? *flag : 0;   // wave-uniform
  if (use32) {
    const float* Arow = (const float*)A + a_off + (size_t)t * 64 * K;
    for (int ci = tid; ci < 64 * K8; ci += 1024) {
      int r_ = ci / K8, c8 = ci % K8;
      const float* p = Arow + r_ * K + c8 * 8;
      floatx4 x0 = *(const floatx4*)p;
      floatx4 x1 = *(const floatx4*)(p + 4);
      short8 s;
#pragma unroll
      for (int j = 0; j < 4; ++j) {
        s[j] = (short)f2bf(x0[j]);
        s[4 + j] = (short)f2bf(x1[j]);
      }
      *(short8*)&As[r_ * RS + c8 * 8] = s;
    }
  } else {
    const unsigned short* Arow = (const unsigned short*)A + a_off + (size_t)t * 64 * K;
    for (int ci = tid; ci < 64 * K8; ci += 1024) {
      int r_ = ci / K8, c8 = ci % K8;
      *(short8*)&As[r_ * RS + c8 * 8] = *(const short8*)&Arow[r_ * K + c8 * 8];
    }
  }
  __syncthreads();
  if (tid >= 512) return;                // waves 8..15 done (no more barriers)
  const int w = tid >> 6;
  const unsigned short* Bp    = slice ? Bb : Bf;
  const unsigned short* biasp = slice ? biasb : biasf;
  const int cb = w * 64;
  const int dslab = slice * 4;
  floatx4 acc[4][4];
#pragma unroll
  for (int m = 0; m < 4; ++m)
#pragma unroll
    for (int n = 0; n < 4; ++n)
#pragma unroll
      for (int r = 0; r < 4; ++r) acc[m][n][r] = 0.f;
#pragma unroll
  for (int ks = 0; ks < K / 32; ++ks) {
    short8 af[4], bfr[4];
#pragma unroll
    for (int m = 0; m < 4; ++m)
      af[m] = *(const short8*)&As[(m * 16 + cc) * RS + ks * 32 + q * 8];
#pragma unroll
    for (int n = 0; n < 4; ++n)
      bfr[n] = *(const short8*)&Bp[(size_t)(cb + n * 16 + cc) * K + ks * 32 + q * 8];
#pragma unroll
    for (int m = 0; m < 4; ++m)
#pragma unroll
      for (int n = 0; n < 4; ++n)
        acc[m][n] = mfma16(af[m], bfr[n], acc[m][n]);
  }
#pragma unroll
  for (int n = 0; n < 4; ++n) {
    const int col = cb + n * 16 + cc;
    const float bv = bf2f(biasp[col]);
#pragma unroll
    for (int m = 0; m < 4; ++m) {
      short4v zv;
#pragma unroll
      for (int r = 0; r < 4; ++r)
        zv[r] = (short)f2bf(acc[m][n][r] + bv);
      *(short4v*)&Z[((size_t)t * 8 + dslab + m) * 8192 + col * 16 + q * 4] = zv;
    }
  }
}

// ---------------------------------------------------------------------------
// FC body (tid<512): block idx covers timesteps idx*2 and idx*2+1.
// ---------------------------------------------------------------------------
__device__ __forceinline__ void fc512_body(
    int idx, int steps, const unsigned short* __restrict__ ys1,
    const unsigned short* __restrict__ fcw, const unsigned short* __restrict__ fcb,
    void* __restrict__ out, size_t out_off, const int* __restrict__ flag)
{
  const int tid = threadIdx.x;
  const int w = tid >> 6, lane = tid & 63;
  const int t = idx * 2 + (w >> 2);
  if (t >= steps) return;
  const int w4 = w & 3;
  const int o = lane & 15, q = lane >> 4;
  const int b = w4 * 16 + o;
  const unsigned short* rp = ys1 + ((size_t)t * 64 + b) * 256 + q * 64;
  float s = 0.f;
#pragma unroll
  for (int j = 0; j < 16; ++j) {
    short4v v = *(const short4v*)(rp + j * 4);
    const unsigned short* wp = fcw + q * 64 + j * 4;
#pragma unroll
    for (int k = 0; k < 4; ++k) s += bf2f((unsigned short)v[k]) * bf2f(wp[k]);
  }
  s += __shfl_xor(s, 16, 64);
  s += __shfl_xor(s, 32, 64);
  if (q == 0) {
    const float v = fsig(s + bf2f(fcb[0]));
    const size_t oidx = out_off + (size_t)t * 64 + b;
    if (*flag) ((float*)out)[oidx] = v;
    else       ((unsigned short*)out)[oidx] = f2bf(v);
  }
}

// ---------------------------------------------------------------------------
// Fused pipeline kernel, 1024-thread blocks (16 waves, 4 waves/SIMD).
// Blocks 0..15: recurrence, ONE ctx per block (round-2's proven register
// regime: bfrag 64 regs -> AGPR, arch VGPR ~64). NEW vs round 2: wave PAIRS
// duplicate the (cheap, non-binding) MFMA tile and SPLIT the pointwise batch
// rows - even wave of a pair handles rows {0,1}, odd {2,3}. Per-wave
// pointwise trans instr halves (28->14), z-prefetch 16->4 VGPRs, creg 4->2,
// so the whole thing fits 128 unified regs at 4 waves/SIMD. Round 2 was
// ~70% dependency bubbles (period 2120 cyc vs ~500 issue floor) with only 2
// lockstep waves/SIMD; doubling resident waves with half-length serial
// sections fills those bubbles. Round-3 lesson applied: never let arch
// VGPR demand exceed the waves_per_eu budget (128-reg ceiling killed the
// two-ctx merge).
// Z prefetch: per ctx, TWO named register sets (A/B), 2x-unrolled loop ->
// vmcnt wait lands two periods after issue.
// Blocks 16+: g96(c+1), g256(c-1), fc(c-3) workers (parity-disjoint buffers).
// ---------------------------------------------------------------------------
__global__ __attribute__((amdgpu_waves_per_eu(4, 4))) __launch_bounds__(1024)
void rec_kernel(
    const unsigned short* __restrict__ Za, const unsigned short* __restrict__ whhfa,
    const unsigned short* __restrict__ whhba,
    unsigned short* __restrict__ ysa, float* __restrict__ ca,
    unsigned short* __restrict__ ha, int inita, int acta,
    const unsigned short* __restrict__ Zb, const unsigned short* __restrict__ whhfb,
    const unsigned short* __restrict__ whhbb,
    unsigned short* __restrict__ ysb, float* __restrict__ cb_,
    unsigned short* __restrict__ hb, int initb, int actb,
    int steps,
    const void* __restrict__ x, size_t x_off, int do96, const int* __restrict__ flag,
    const unsigned short* __restrict__ wih0f, const unsigned short* __restrict__ wih0b,
    const unsigned short* __restrict__ b0f, const unsigned short* __restrict__ b0b,
    unsigned short* __restrict__ Z0n,
    const unsigned short* __restrict__ ys0g, int do256,
    const unsigned short* __restrict__ wih1f, const unsigned short* __restrict__ wih1b,
    const unsigned short* __restrict__ b1f, const unsigned short* __restrict__ b1b,
    unsigned short* __restrict__ Z1n,
    const unsigned short* __restrict__ fcsrc,
    const unsigned short* __restrict__ fcw, const unsigned short* __restrict__ fcb,
    void* __restrict__ out, size_t fc_off, int fcn)
{
  __shared__ __align__(16) unsigned char smem[34816];
  const int bx = blockIdx.x;
  const int g96n = steps * 2;

  if (bx >= 16) {
    const int wi = bx - 16;
    if (wi < g96n) {                       // g96 (next chunk L0)
      if (!do96) return;
      gemm1024_body<96>((unsigned short*)smem, wi >> 1, wi & 1, x, x_off, 1,
                        flag, wih0f, wih0b, b0f, b0b, Z0n);
    } else if (wi < 2 * g96n) {            // g256 (L1 chunk c-1)
      if (!do256) return;
      const int idx = wi - g96n;
      gemm1024_body<256>((unsigned short*)smem, idx >> 1, idx & 1, ys0g, 0, 0,
                         flag, wih1f, wih1b, b1f, b1b, Z1n);
    } else {                               // fc (chunk c-3)
      if (fcn <= 0) return;
      if (threadIdx.x < 512)
        fc512_body(wi - 2 * g96n, steps, fcsrc, fcw, fcb, out, fc_off, flag);
    }
    return;
  }

  // ---- recurrence path (one ctx per block, 16 waves) ----
  const int blk = bx;
  if (blk < 8 ? !acta : !actb) return;
  const int tid = threadIdx.x;

  const unsigned short* Z;
  const unsigned short* whhF;
  const unsigned short* whhB;
  unsigned short* ys;
  float* cst;
  unsigned short* hst;
  int init;
  if (blk < 8) {
    Z = Za; whhF = whhfa; whhB = whhba; ys = ysa; cst = ca; hst = ha; init = inita;
  } else {
    Z = Zb; whhF = whhfb; whhB = whhbb; ys = ysb; cst = cb_; hst = hb; init = initb;
  }
  const int d = (blk >> 2) & 1, bg = blk & 3;
  const unsigned short* whh = d ? whhB : whhF;

  unsigned short (*hbuf)[16][136] = (unsigned short(*)[16][136])smem;

  const int lane = tid & 63, q = lane >> 4, cc = lane & 15;
  const int p = tid >> 7;            // wave pair id 0..7 -> u-block
  const int half = (tid >> 6) & 1;   // 0: batch rows {0,1}; 1: rows {2,3}
  const int u = p * 16 + cc;

  // Whh as MFMA B-fragments, register-resident (64 regs -> AGPR file).
  short8 bfrag[4][4];
#pragma unroll
  for (int g = 0; g < 4; ++g)
#pragma unroll
    for (int k = 0; k < 4; ++k)
      bfrag[g][k] = *(const short8*)(whh + (size_t)(g * 128 + u) * 128 + k * 32 + q * 8);

  float creg[2];                     // 2 cell rows/thread, 2*log2(e)*c domain
  const int row = tid >> 5;          // (tid<512 helpers) 0..15
  const int col4 = (tid & 31) * 4;   // 0..124
  if (init) {
#pragma unroll
    for (int r = 0; r < 2; ++r) creg[r] = 0.f;
    if (tid < 512) {
      short4v zz = {0, 0, 0, 0};
      *(short4v*)&hbuf[0][row][col4] = zz;
    }
  } else {
#pragma unroll
    for (int r = 0; r < 2; ++r)
      creg[r] = cst[(size_t)(d * 64 + bg * 16 + q * 4 + half * 2 + r) * 128 + u];
    if (tid < 512)
      *(short4v*)&hbuf[0][row][col4] =
          *(const short4v*)(hst + (size_t)(d * 64 + bg * 16 + row) * 128 + col4);
  }
  __syncthreads();

  // per-thread z: 2 batch rows (half*2 + {0,1}) packed as one dword per gate
  const size_t zbase = (size_t)(d * 4 + bg) * 8192 + u * 16 + q * 4 + half * 2;
  const unsigned short* zpA = Z + zbase;            // even-step addresses
  const unsigned short* zpB = Z + zbase + 65536;    // odd-step addresses
  unsigned zA[4], zB[4];
#pragma unroll
  for (int g = 0; g < 4; ++g) zA[g] = *(const unsigned*)(zpA + g * 2048);
#pragma unroll
  for (int g = 0; g < 4; ++g) zB[g] = *(const unsigned*)(zpB + g * 2048);
  zpA += 131072;
  zpB += 131072;

  unsigned short* ysb_ = ys + (size_t)(bg * 16 + row) * 256 + d * 128 + col4;

  // one timestep; cur/nxt compile-time at each call site.
  auto half_step = [&](unsigned (&zs)[4], const unsigned short*& zp, int t,
                       int cur, int nxt) __attribute__((always_inline)) {
    floatx4 acc[4];
    if (half == 0) {                 // wave-uniform branch
#pragma unroll
      for (int g = 0; g < 4; ++g) {
        acc[g][0] = __builtin_bit_cast(float, zs[g] << 16);
        acc[g][1] = __builtin_bit_cast(float, zs[g] & 0xFFFF0000u);
        acc[g][2] = 0.f; acc[g][3] = 0.f;
      }
    } else {
#pragma unroll
      for (int g = 0; g < 4; ++g) {
        acc[g][0] = 0.f; acc[g][1] = 0.f;
        acc[g][2] = __builtin_bit_cast(float, zs[g] << 16);
        acc[g][3] = __builtin_bit_cast(float, zs[g] & 0xFFFF0000u);
      }
    }
    // prefetch this set's t+2 data; vmcnt wait is two periods away
#pragma unroll
    for (int g = 0; g < 4; ++g) zs[g] = *(const unsigned*)(zp + g * 2048);
    zp += 131072;

    short8 af[4];
#pragma unroll
    for (int k = 0; k < 4; ++k)
      af[k] = *(const short8*)&hbuf[cur][cc][k * 32 + q * 8];
#pragma unroll
    for (int g = 0; g < 4; ++g)
#pragma unroll
      for (int k = 0; k < 4; ++k)
        acc[g] = mfma16(af[k], bfrag[g][k], acc[g]);

    // fused pointwise on the 2 owned rows: 5 exp2 + 2 rcp per row.
    auto pw2 = [&](int ra) __attribute__((always_inline)) {
#pragma unroll
      for (int j = 0; j < 2; ++j) {
        const int rr = ra + j;
        const float ei = fast_exp2(acc[0][rr]);
        const float ef = fast_exp2(acc[1][rr]);
        const float eg = fast_exp2(acc[2][rr]);
        const float a1 = 1.0f + ei, a2 = 1.0f + eg, a3 = 1.0f + ef;
        const float p12 = a1 * a2;
        const float rD = fast_rcp(p12 * a3);
        const float t2 = __builtin_fmaf(eg, 2.0f * LOG2E, -2.0f * LOG2E);
        const float it2 = ei * t2 * (a3 * rD);     // 2L * sig(i)*tanh(g)
        const float sf = ef * (p12 * rD);          // sig(f)
        const float cs = __builtin_fmaf(sf, creg[j], it2);
        creg[j] = cs;
        const float eo = fast_exp2(acc[3][rr]);
        const float ec = fast_exp2(fminf(cs, 88.0f));  // e^{2c}
        const float h = eo * (ec - 1.0f) * fast_rcp((1.0f + eo) * (1.0f + ec));
        hbuf[nxt][q * 4 + rr][u] = f2bf(h);
      }
    };
    if (half == 0) pw2(0); else pw2(2);

    // LDS-only barrier: drain ds ops; z prefetch (vmcnt) stays in flight
    asm volatile("s_waitcnt lgkmcnt(0)\n\ts_barrier" ::: "memory");
    // drain ys row t (h produced this step) - fire-and-forget store
    if (tid < 512) {
      short4v hv = *(const short4v*)&hbuf[nxt][row][col4];
      *(short4v*)(ysb_ + (size_t)t * 16384) = hv;
    }
  };

  int t = 0;
  for (; t + 2 <= steps; t += 2) {
    half_step(zA, zpA, t, 0, 1);
    half_step(zB, zpB, t + 1, 1, 0);
  }
  if (t < steps)                      // odd-step tail (C=1 fallback only)
    half_step(zA, zpA, t, 0, 1);

#pragma unroll
  for (int r = 0; r < 2; ++r)
    cst[(size_t)(d * 64 + bg * 16 + q * 4 + half * 2 + r) * 128 + u] = creg[r];
  const int fin = steps & 1;
  if (tid < 512)
    *(short4v*)(hst + (size_t)(d * 64 + bg * 16 + row) * 128 + col4) =
        *(const short4v*)&hbuf[fin][row][col4];
}

// ---------------------------------------------------------------------------
// Standalone gemm96 (chunk 0 prologue). Grid 2C x 1024.
// ---------------------------------------------------------------------------
__global__ __attribute__((amdgpu_waves_per_eu(4, 4))) __launch_bounds__(1024)
void g96_kernel(
    const void* __restrict__ x, size_t x_off, const int* __restrict__ flag,
    const unsigned short* __restrict__ Bf, const unsigned short* __restrict__ Bb,
    const unsigned short* __restrict__ biasf, const unsigned short* __restrict__ biasb,
    unsigned short* __restrict__ Z)
{
  __shared__ __align__(16) unsigned short As[64 * 104];
  gemm1024_body<96>(As, blockIdx.x >> 1, blockIdx.x & 1, x, x_off, 1, flag,
                    Bf, Bb, biasf, biasb, Z);
}

// ---------------------------------------------------------------------------
// Standalone FC (final chunk). One wave per (t,b).
// ---------------------------------------------------------------------------
__global__ __launch_bounds__(256) void fc_kernel(
    const unsigned short* __restrict__ ys,
    const unsigned short* __restrict__ fcw,
    const unsigned short* __restrict__ fcb,
    void* __restrict__ out, size_t out_off, int n,
    const int* __restrict__ flag)
{
  const int gw = (int)((blockIdx.x * 256 + threadIdx.x) >> 6);
  const int lane = threadIdx.x & 63;
  if (gw >= n) return;
  const unsigned short* rp = ys + (size_t)gw * 256 + lane * 4;
  float s = 0.f;
#pragma unroll
  for (int i = 0; i < 4; ++i) s += bf2f(rp[i]) * bf2f(fcw[lane * 4 + i]);
#pragma unroll
  for (int m = 32; m >= 1; m >>= 1) s += __shfl_xor(s, m, 64);
  if (lane == 0) {
    const float v = fsig(s + bf2f(fcb[0]));
    if (*flag) ((float*)out)[out_off + gw] = v;
    else       ((unsigned short*)out)[out_off + gw] = f2bf(v);
  }
}

extern "C" void kernel_launch(void* const* d_in, const int* in_sizes, int n_in,
                              void* d_out, int out_size, void* d_ws, size_t ws_size,
                              hipStream_t stream)
{
  (void)in_sizes; (void)n_in; (void)out_size;
  const int S = 4096;

  int* flag = (int*)d_ws;
  unsigned short* wbuf = (unsigned short*)((char*)d_ws + 256);
  static const int woff[14] = {0,      49152,  114688, 115200, 164352, 229888,
                               230400, 361472, 427008, 427520, 558592, 624128,
                               624640, 624896};
  const size_t wbuf_end = 256 + 1250304;  // bytes

  // Double buffers: Z0/Z1 2*C*131072 B each, ys0/ys1 2*C*32768 each
  // -> C*655360 B.
  int C = 1;
  for (int cand = 128; cand >= 1; cand >>= 1) {
    size_t need = (size_t)cand * 655360 + wbuf_end + 196608;
    if (need <= ws_size) { C = cand; break; }
  }
  unsigned short* base = (unsigned short*)((char*)d_ws + wbuf_end);
  unsigned short* Z0buf[2] = {base, base + (size_t)C * 65536};
  unsigned short* Z1buf[2] = {base + (size_t)2 * C * 65536, base + (size_t)3 * C * 65536};
  unsigned short* ys0buf[2] = {base + (size_t)4 * C * 65536,
                               base + (size_t)4 * C * 65536 + (size_t)C * 16384};
  unsigned short* ys1buf[2] = {base + (size_t)4 * C * 65536 + (size_t)2 * C * 16384,
                               base + (size_t)4 * C * 65536 + (size_t)3 * C * 16384};
  float* c0 = (float*)(base + (size_t)4 * C * 65536 + (size_t)4 * C * 16384);
  float* c1 = c0 + 16384;
  unsigned short* h0 = (unsigned short*)(c1 + 16384);
  unsigned short* h1 = h0 + 16384;

  const unsigned short* wih0f = wbuf + woff[0];
  const unsigned short* whh0f = wbuf + woff[1];
  const unsigned short* b0f   = wbuf + woff[2];
  const unsigned short* wih0b = wbuf + woff[3];
  const unsigned short* whh0b = wbuf + woff[4];
  const unsigned short* b0b   = wbuf + woff[5];
  const unsigned short* wih1f = wbuf + woff[6];
  const unsigned short* whh1f = wbuf + woff[7];
  const unsigned short* b1f   = wbuf + woff[8];
  const unsigned short* wih1b = wbuf + woff[9];
  const unsigned short* whh1b = wbuf + woff[10];
  const unsigned short* b1b   = wbuf + woff[11];
  const unsigned short* fcw   = wbuf + woff[12];
  const unsigned short* fcb   = wbuf + woff[13];

  detect_kernel<<<1, 256, 0, stream>>>((const unsigned short*)d_in[1], 49152, flag);
  convertw_kernel<<<614, 256, 0, stream>>>(
      d_in[1], d_in[2], d_in[3], d_in[4], d_in[5], d_in[6], d_in[7],
      d_in[8], d_in[9], d_in[10], d_in[11], d_in[12], d_in[13], d_in[14],
      wbuf, flag);

  const int nc = S / C;
  // prologue: gemm96 for chunk 0
  g96_kernel<<<C * 2, 1024, 0, stream>>>(d_in[0], 0, flag,
                                         wih0f, wih0b, b0f, b0b, Z0buf[0]);

  const int GX = 16 + 4 * C + (C + 1) / 2;
  for (int c = 0; c <= nc + 1; ++c) {
    const int p = c & 1, pn = (c + 1) & 1;  // pn == (c-1)&1 == (c+1)&1
    rec_kernel<<<GX, 1024, 0, stream>>>(
        // ctx a: L0 chunk c
        Z0buf[p], whh0f, whh0b, ys0buf[p], c0, h0, (c == 0) ? 1 : 0,
        (c <= nc - 1) ? 1 : 0,
        // ctx b: L1 chunk c-2
        Z1buf[p], whh1f, whh1b, ys1buf[p], c1, h1, (c == 2) ? 1 : 0,
        (c >= 2) ? 1 : 0,
        C,
        // embedded g96: chunk c+1
        d_in[0], (size_t)(c + 1) * C * 6144, (c <= nc - 2) ? 1 : 0, flag,
        wih0f, wih0b, b0f, b0b, Z0buf[pn],
        // embedded g256: chunk c-1 (ys0[(c-1)&1] -> Z1[(c-1)&1])
        ys0buf[pn], (c >= 1 && c <= nc) ? 1 : 0, wih1f, wih1b, b1f, b1b, Z1buf[pn],
        // embedded fc: chunk c-3 (reads ys1[(c-3)&1])
        ys1buf[pn], fcw, fcb, d_out,
        (c >= 3) ? (size_t)(c - 3) * C * 64 : 0, (c >= 3) ? C * 64 : 0);
  }
  // tail fc: chunk nc-1 (written during rec launch nc+1)
  fc_kernel<<<C * 16, 256, 0, stream>>>(ys1buf[(nc - 1) & 1], fcw, fcb, d_out,
                                        (size_t)(nc - 1) * C * 64, C * 64, flag);
}

// Round 6
// 5027.559 us; speedup vs baseline: 1.6788x; 1.6498x over previous
//
#include <hip/hip_runtime.h>
#include <stdint.h>

typedef short short8 __attribute__((ext_vector_type(8)));
typedef short short4v __attribute__((ext_vector_type(4)));
typedef float floatx4 __attribute__((ext_vector_type(4)));

#define LOG2E 1.44269504088896340736f

__device__ __forceinline__ float bf2f(unsigned short u) {
  unsigned v = ((unsigned)u) << 16;
  return __builtin_bit_cast(float, v);
}
__device__ __forceinline__ unsigned short f2bf(float f) {
  unsigned v = __builtin_bit_cast(unsigned, f);
  v += 0x7FFFu + ((v >> 16) & 1u);   // RNE
  return (unsigned short)(v >> 16);
}
__device__ __forceinline__ float fast_exp2(float x) {
#if __has_builtin(__builtin_amdgcn_exp2f)
  return __builtin_amdgcn_exp2f(x);
#else
  return exp2f(x);
#endif
}
__device__ __forceinline__ float fast_rcp(float x) {
#if __has_builtin(__builtin_amdgcn_rcpf)
  return __builtin_amdgcn_rcpf(x);
#else
  return 1.0f / x;
#endif
}
__device__ __forceinline__ float fsig(float x) {
  return fast_rcp(1.0f + fast_exp2(-LOG2E * x));
}
__device__ __forceinline__ floatx4 mfma16(short8 a, short8 b, floatx4 c) {
  return __builtin_amdgcn_mfma_f32_16x16x32_bf16(a, b, c, 0, 0, 0);
}

// ---------------------------------------------------------------------------
// Dtype detection: f32 buffers show even-u16 "exponent" >= 0xF0 often; bf16
// 0.05-scaled weights never do. flag: 1 = f32, 0 = bf16.
// ---------------------------------------------------------------------------
__global__ __launch_bounds__(256) void detect_kernel(
    const unsigned short* __restrict__ w, int n_u16, int* __restrict__ flag)
{
  __shared__ int cnt;
  if (threadIdx.x == 0) cnt = 0;
  __syncthreads();
  int local = 0;
  for (int i = threadIdx.x * 2; i < n_u16; i += 512) {
    unsigned e = (w[i] >> 7) & 0xFF;
    if (e >= 0xF0) local++;
  }
  atomicAdd(&cnt, local);
  __syncthreads();
  if (threadIdx.x == 0) *flag = (cnt > 64) ? 1 : 0;
}

// ---------------------------------------------------------------------------
// One merged kernel canonicalizing all 14 weight tensors to bf16 in ws.
// Gate-block pre-scaling: i/f/o rows (and biases) scaled by log2(e), g rows
// by 2*log2(e) -> recurrence needs only bare exp2; cell state carried in the
// 2*log2(e)*c domain. fc weights (12,13) stay unscaled.
// ---------------------------------------------------------------------------
__global__ __launch_bounds__(256) void convertw_kernel(
    const void* s0, const void* s1, const void* s2, const void* s3,
    const void* s4, const void* s5, const void* s6, const void* s7,
    const void* s8, const void* s9, const void* s10, const void* s11,
    const void* s12, const void* s13,
    unsigned short* __restrict__ wbuf, const int* __restrict__ flag)
{
  const void* srcs[14] = {s0, s1, s2, s3, s4, s5, s6, s7, s8, s9, s10, s11, s12, s13};
  const int woff[14] = {0,      49152,  114688, 115200, 164352, 229888,
                        230400, 361472, 427008, 427520, 558592, 624128,
                        624640, 624896};
  const int wlen[14] = {49152, 65536, 512, 49152, 65536, 512,
                        131072, 65536, 512, 131072, 65536, 512, 256, 1};
  const int glen[14] = {96 * 128, 128 * 128, 128, 96 * 128, 128 * 128, 128,
                        256 * 128, 128 * 128, 128, 256 * 128, 128 * 128, 128,
                        0, 0};
  int sb = 0, i = 0;
  for (i = 0; i < 14; ++i) {
    int nb = (wlen[i] + 1023) >> 10;
    if ((int)blockIdx.x < sb + nb) break;
    sb += nb;
  }
  const int base = ((int)blockIdx.x - sb) * 1024 + (int)threadIdx.x * 4;
  unsigned short* dst = wbuf + woff[i];
  const int f32 = *flag;
  const int gl = glen[i];
#pragma unroll
  for (int j = 0; j < 4; ++j) {
    const int idx = base + j;
    if (idx >= wlen[i]) break;
    float v = f32 ? ((const float*)srcs[i])[idx]
                  : bf2f(((const unsigned short*)srcs[i])[idx]);
    if (gl) {
      const int gate = (int)((unsigned)idx / (unsigned)gl);  // row >> 7
      v *= (gate == 2) ? (2.0f * LOG2E) : LOG2E;
    }
    dst[idx] = f2bf(v);
  }
}

// ---------------------------------------------------------------------------
// GEMM body for 512-thread blocks: all 8 waves stage A into LDS, then all 8
// compute 512 cols (8 waves x 64). Z output bf16, BG-MAJOR
// [t][dir][bg][512 cols][16 b]. (Weights pre-scaled.)
// ---------------------------------------------------------------------------
template <int K>
__device__ __forceinline__ void gemm512_body(
    unsigned short* As, int t, int slice,
    const void* __restrict__ A, size_t a_off, int dyn,
    const int* __restrict__ flag,
    const unsigned short* __restrict__ Bf, const unsigned short* __restrict__ Bb,
    const unsigned short* __restrict__ biasf, const unsigned short* __restrict__ biasb,
    unsigned short* __restrict__ Z)
{
  constexpr int RS = K + 8;
  const int tid = threadIdx.x, lane = tid & 63;
  const int q = lane >> 4, cc = lane & 15;
  constexpr int K8 = K / 8;
  const int use32 = dyn ? *flag : 0;   // wave-uniform
  if (use32) {
    const float* Arow = (const float*)A + a_off + (size_t)t * 64 * K;
    for (int ci = tid; ci < 64 * K8; ci += 512) {
      int r_ = ci / K8, c8 = ci % K8;
      const float* p = Arow + r_ * K + c8 * 8;
      floatx4 x0 = *(const floatx4*)p;
      floatx4 x1 = *(const floatx4*)(p + 4);
      short8 s;
#pragma unroll
      for (int j = 0; j < 4; ++j) {
        s[j] = (short)f2bf(x0[j]);
        s[4 + j] = (short)f2bf(x1[j]);
      }
      *(short8*)&As[r_ * RS + c8 * 8] = s;
    }
  } else {
    const unsigned short* Arow = (const unsigned short*)A + a_off + (size_t)t * 64 * K;
    for (int ci = tid; ci < 64 * K8; ci += 512) {
      int r_ = ci / K8, c8 = ci % K8;
      *(short8*)&As[r_ * RS + c8 * 8] = *(const short8*)&Arow[r_ * K + c8 * 8];
    }
  }
  __syncthreads();
  const int w = tid >> 6;
  const unsigned short* Bp    = slice ? Bb : Bf;
  const unsigned short* biasp = slice ? biasb : biasf;
  const int cb = w * 64;
  const int dslab = slice * 4;
  floatx4 acc[4][4];
#pragma unroll
  for (int m = 0; m < 4; ++m)
#pragma unroll
    for (int n = 0; n < 4; ++n)
#pragma unroll
      for (int r = 0; r < 4; ++r) acc[m][n][r] = 0.f;
#pragma unroll
  for (int ks = 0; ks < K / 32; ++ks) {
    short8 af[4], bfr[4];
#pragma unroll
    for (int m = 0; m < 4; ++m)
      af[m] = *(const short8*)&As[(m * 16 + cc) * RS + ks * 32 + q * 8];
#pragma unroll
    for (int n = 0; n < 4; ++n)
      bfr[n] = *(const short8*)&Bp[(size_t)(cb + n * 16 + cc) * K + ks * 32 + q * 8];
#pragma unroll
    for (int m = 0; m < 4; ++m)
#pragma unroll
      for (int n = 0; n < 4; ++n)
        acc[m][n] = mfma16(af[m], bfr[n], acc[m][n]);
  }
#pragma unroll
  for (int n = 0; n < 4; ++n) {
    const int col = cb + n * 16 + cc;
    const float bv = bf2f(biasp[col]);
#pragma unroll
    for (int m = 0; m < 4; ++m) {
      short4v zv;
#pragma unroll
      for (int r = 0; r < 4; ++r)
        zv[r] = (short)f2bf(acc[m][n][r] + bv);
      *(short4v*)&Z[((size_t)t * 8 + dslab + m) * 8192 + col * 16 + q * 4] = zv;
    }
  }
}

// ---------------------------------------------------------------------------
// FC body (512 threads): block idx covers timesteps idx*2 and idx*2+1.
// ---------------------------------------------------------------------------
__device__ __forceinline__ void fc512_body(
    int idx, int steps, const unsigned short* __restrict__ ys1,
    const unsigned short* __restrict__ fcw, const unsigned short* __restrict__ fcb,
    void* __restrict__ out, size_t out_off, const int* __restrict__ flag)
{
  const int tid = threadIdx.x;
  const int w = tid >> 6, lane = tid & 63;
  const int t = idx * 2 + (w >> 2);
  if (t >= steps) return;
  const int w4 = w & 3;
  const int o = lane & 15, q = lane >> 4;
  const int b = w4 * 16 + o;
  const unsigned short* rp = ys1 + ((size_t)t * 64 + b) * 256 + q * 64;
  float s = 0.f;
#pragma unroll
  for (int j = 0; j < 16; ++j) {
    short4v v = *(const short4v*)(rp + j * 4);
    const unsigned short* wp = fcw + q * 64 + j * 4;
#pragma unroll
    for (int k = 0; k < 4; ++k) s += bf2f((unsigned short)v[k]) * bf2f(wp[k]);
  }
  s += __shfl_xor(s, 16, 64);
  s += __shfl_xor(s, 32, 64);
  if (q == 0) {
    const float v = fsig(s + bf2f(fcb[0]));
    const size_t oidx = out_off + (size_t)t * 64 + b;
    if (*flag) ((float*)out)[oidx] = v;
    else       ((unsigned short*)out)[oidx] = f2bf(v);
  }
}

// ---------------------------------------------------------------------------
// Fused pipeline kernel, 512-thread blocks (8 waves, 2 waves/SIMD - the
// proven round-2 regime; rounds 3/4 showed that in a per-step-barrier
// lockstep structure, MORE waves/SIMD extend the barrier tail instead of
// filling bubbles, and 2x bfrag blows the register budget).
// Blocks 0..31: recurrence, BATCH-SPLIT 2x: block = (ctx, d, bg, bh). The
// recurrence couples hidden units, NOT batch rows, and all batch rows share
// the SAME Whh -> splitting each (layer,dir,bg) slice across two CUs by
// batch (8 rows each) halves per-wave pointwise (28->14 trans), z-regs and
// creg at ZERO extra bfrag cost (the round-3 trap needed a 2nd 64-reg Whh;
// batch-split needs none). bh selects acc register rows: bh=0 -> rows
// {0,1} of each q-quad (batch q*4+0,1), bh=1 -> rows {2,3}. Foreign rows in
// hbuf stay zero (MFMA is row-isolated -> no NaN leakage); their D rows are
// computed and discarded (MFMA pipe is not binding).
// Z prefetch: TWO named register sets (A/B), 2x-unrolled loop -> vmcnt wait
// lands two periods after issue.
// Blocks 32+: g96(c+1), g256(c-1), fc(c-3) workers (parity-disjoint buffers).
// ---------------------------------------------------------------------------
__global__ __attribute__((amdgpu_waves_per_eu(2, 4))) __launch_bounds__(512)
void rec_kernel(
    const unsigned short* __restrict__ Za, const unsigned short* __restrict__ whhfa,
    const unsigned short* __restrict__ whhba,
    unsigned short* __restrict__ ysa, float* __restrict__ ca,
    unsigned short* __restrict__ ha, int inita, int acta,
    const unsigned short* __restrict__ Zb, const unsigned short* __restrict__ whhfb,
    const unsigned short* __restrict__ whhbb,
    unsigned short* __restrict__ ysb, float* __restrict__ cb_,
    unsigned short* __restrict__ hb, int initb, int actb,
    int steps,
    const void* __restrict__ x, size_t x_off, int do96, const int* __restrict__ flag,
    const unsigned short* __restrict__ wih0f, const unsigned short* __restrict__ wih0b,
    const unsigned short* __restrict__ b0f, const unsigned short* __restrict__ b0b,
    unsigned short* __restrict__ Z0n,
    const unsigned short* __restrict__ ys0g, int do256,
    const unsigned short* __restrict__ wih1f, const unsigned short* __restrict__ wih1b,
    const unsigned short* __restrict__ b1f, const unsigned short* __restrict__ b1b,
    unsigned short* __restrict__ Z1n,
    const unsigned short* __restrict__ fcsrc,
    const unsigned short* __restrict__ fcw, const unsigned short* __restrict__ fcb,
    void* __restrict__ out, size_t fc_off, int fcn)
{
  __shared__ __align__(16) unsigned char smem[34816];
  const int bx = blockIdx.x;
  const int g96n = steps * 2;

  if (bx >= 32) {
    const int wi = bx - 32;
    if (wi < g96n) {                       // g96 (next chunk L0)
      if (!do96) return;
      gemm512_body<96>((unsigned short*)smem, wi >> 1, wi & 1, x, x_off, 1,
                       flag, wih0f, wih0b, b0f, b0b, Z0n);
    } else if (wi < 2 * g96n) {            // g256 (L1 chunk c-1)
      if (!do256) return;
      const int idx = wi - g96n;
      gemm512_body<256>((unsigned short*)smem, idx >> 1, idx & 1, ys0g, 0, 0,
                        flag, wih1f, wih1b, b1f, b1b, Z1n);
    } else {                               // fc (chunk c-3)
      if (fcn <= 0) return;
      fc512_body(wi - 2 * g96n, steps, fcsrc, fcw, fcb, out, fc_off, flag);
    }
    return;
  }

  // ---- recurrence path: block = (ctx, d, bg, bh) ----
  const int blk = bx;
  const int ctx = blk >> 4;
  if (ctx == 0 ? !acta : !actb) return;
  const int tid = threadIdx.x;

  const unsigned short* Z;
  const unsigned short* whhF;
  const unsigned short* whhB;
  unsigned short* ys;
  float* cst;
  unsigned short* hst;
  int init;
  if (ctx == 0) {
    Z = Za; whhF = whhfa; whhB = whhba; ys = ysa; cst = ca; hst = ha; init = inita;
  } else {
    Z = Zb; whhF = whhfb; whhB = whhbb; ys = ysb; cst = cb_; hst = hb; init = initb;
  }
  const int d = (blk >> 3) & 1, bg = (blk >> 1) & 3, bh = blk & 1;
  const unsigned short* whh = d ? whhB : whhF;

  unsigned short (*hbuf)[16][136] = (unsigned short(*)[16][136])smem;

  const int w = tid >> 6, lane = tid & 63, q = lane >> 4, cc = lane & 15;
  const int u = w * 16 + cc;
  const int rb = bh * 2;             // acc register rows rb, rb+1 are ours

  // Whh as MFMA B-fragments, register-resident (64 regs -> AGPR file).
  short8 bfrag[4][4];
#pragma unroll
  for (int g = 0; g < 4; ++g)
#pragma unroll
    for (int k = 0; k < 4; ++k)
      bfrag[g][k] = *(const short8*)(whh + (size_t)(g * 128 + u) * 128 + k * 32 + q * 8);

  // drain/load lane mapping: 8 owned rows, physical row = q'*4 + bh*2 + j
  const int rowp = tid >> 6;                         // 0..7
  const int prow = (rowp >> 1) * 4 + bh * 2 + (rowp & 1);
  const int col2 = (tid & 63) * 2;                   // 0..126 even

  // zero BOTH hbuf buffers (foreign-bh rows must read as 0 forever)
  {
    unsigned* hz = (unsigned*)smem;
    for (int i = tid; i < 2 * 16 * 68; i += 512) hz[i] = 0u;
  }
  __syncthreads();

  float creg[2];                     // 2 cell rows/thread, 2*log2(e)*c domain
  if (init) {
#pragma unroll
    for (int j = 0; j < 2; ++j) creg[j] = 0.f;
  } else {
#pragma unroll
    for (int j = 0; j < 2; ++j)
      creg[j] = cst[(size_t)(d * 64 + bg * 16 + q * 4 + rb + j) * 128 + u];
    *(unsigned*)&hbuf[0][prow][col2] =
        *(const unsigned*)(hst + (size_t)(d * 64 + bg * 16 + prow) * 128 + col2);
  }
  __syncthreads();

  // per-thread z: 2 batch rows (q*4 + rb + {0,1}) = one dword per gate
  const size_t zbase = (size_t)(d * 4 + bg) * 8192 + u * 16 + q * 4 + rb;
  const unsigned short* zpA = Z + zbase;            // even-step addresses
  const unsigned short* zpB = Z + zbase + 65536;    // odd-step addresses
  unsigned zA[4], zB[4];
#pragma unroll
  for (int g = 0; g < 4; ++g) zA[g] = *(const unsigned*)(zpA + g * 2048);
#pragma unroll
  for (int g = 0; g < 4; ++g) zB[g] = *(const unsigned*)(zpB + g * 2048);
  zpA += 131072;
  zpB += 131072;

  unsigned short* ysb_ = ys + (size_t)(bg * 16 + prow) * 256 + d * 128 + col2;

  // one timestep; cur/nxt compile-time at each call site.
  auto half_step = [&](unsigned (&zs)[4], const unsigned short*& zp, int t,
                       int cur, int nxt) __attribute__((always_inline)) {
    floatx4 acc[4];
    if (bh == 0) {                   // block-uniform branch
#pragma unroll
      for (int g = 0; g < 4; ++g) {
        acc[g][0] = __builtin_bit_cast(float, zs[g] << 16);
        acc[g][1] = __builtin_bit_cast(float, zs[g] & 0xFFFF0000u);
        acc[g][2] = 0.f; acc[g][3] = 0.f;
      }
    } else {
#pragma unroll
      for (int g = 0; g < 4; ++g) {
        acc[g][0] = 0.f; acc[g][1] = 0.f;
        acc[g][2] = __builtin_bit_cast(float, zs[g] << 16);
        acc[g][3] = __builtin_bit_cast(float, zs[g] & 0xFFFF0000u);
      }
    }
    // prefetch this set's t+2 data; vmcnt wait is two periods away
#pragma unroll
    for (int g = 0; g < 4; ++g) zs[g] = *(const unsigned*)(zp + g * 2048);
    zp += 131072;

    short8 af[4];
#pragma unroll
    for (int k = 0; k < 4; ++k)
      af[k] = *(const short8*)&hbuf[cur][cc][k * 32 + q * 8];
#pragma unroll
    for (int g = 0; g < 4; ++g)
#pragma unroll
      for (int k = 0; k < 4; ++k)
        acc[g] = mfma16(af[k], bfrag[g][k], acc[g]);

    // fused pointwise on the 2 owned rows: 5 exp2 + 2 rcp per row.
#pragma unroll
    for (int j = 0; j < 2; ++j) {
      const int rr = rb + j;
      const float ei = fast_exp2(acc[0][rr]);
      const float ef = fast_exp2(acc[1][rr]);
      const float eg = fast_exp2(acc[2][rr]);
      const float a1 = 1.0f + ei, a2 = 1.0f + eg, a3 = 1.0f + ef;
      const float p12 = a1 * a2;
      const float rD = fast_rcp(p12 * a3);
      const float t2 = __builtin_fmaf(eg, 2.0f * LOG2E, -2.0f * LOG2E);
      const float it2 = ei * t2 * (a3 * rD);       // 2L * sig(i)*tanh(g)
      const float sf = ef * (p12 * rD);            // sig(f)
      const float cs = __builtin_fmaf(sf, creg[j], it2);
      creg[j] = cs;
      const float eo = fast_exp2(acc[3][rr]);
      const float ec = fast_exp2(fminf(cs, 88.0f));  // e^{2c}
      const float h = eo * (ec - 1.0f) * fast_rcp((1.0f + eo) * (1.0f + ec));
      hbuf[nxt][q * 4 + rr][u] = f2bf(h);
    }
    // LDS-only barrier: drain ds ops; z prefetch (vmcnt) stays in flight
    asm volatile("s_waitcnt lgkmcnt(0)\n\ts_barrier" ::: "memory");
    // drain ys rows t (this block's 8 rows) - fire-and-forget store
    unsigned hv = *(const unsigned*)&hbuf[nxt][prow][col2];
    *(unsigned*)(ysb_ + (size_t)t * 16384) = hv;
  };

  int t = 0;
  for (; t + 2 <= steps; t += 2) {
    half_step(zA, zpA, t, 0, 1);
    half_step(zB, zpB, t + 1, 1, 0);
  }
  if (t < steps)                      // odd-step tail (C=1 fallback only)
    half_step(zA, zpA, t, 0, 1);

#pragma unroll
  for (int j = 0; j < 2; ++j)
    cst[(size_t)(d * 64 + bg * 16 + q * 4 + rb + j) * 128 + u] = creg[j];
  const int fin = steps & 1;
  *(unsigned*)(hst + (size_t)(d * 64 + bg * 16 + prow) * 128 + col2) =
      *(const unsigned*)&hbuf[fin][prow][col2];
}

// ---------------------------------------------------------------------------
// Standalone gemm96 (chunk 0 prologue). Grid 2C x 512.
// ---------------------------------------------------------------------------
__global__ __attribute__((amdgpu_waves_per_eu(2, 4))) __launch_bounds__(512)
void g96_kernel(
    const void* __restrict__ x, size_t x_off, const int* __restrict__ flag,
    const unsigned short* __restrict__ Bf, const unsigned short* __restrict__ Bb,
    const unsigned short* __restrict__ biasf, const unsigned short* __restrict__ biasb,
    unsigned short* __restrict__ Z)
{
  __shared__ __align__(16) unsigned short As[64 * 104];
  gemm512_body<96>(As, blockIdx.x >> 1, blockIdx.x & 1, x, x_off, 1, flag,
                   Bf, Bb, biasf, biasb, Z);
}

// ---------------------------------------------------------------------------
// Standalone FC (final chunk). One wave per (t,b).
// ---------------------------------------------------------------------------
__global__ __launch_bounds__(256) void fc_kernel(
    const unsigned short* __restrict__ ys,
    const unsigned short* __restrict__ fcw,
    const unsigned short* __restrict__ fcb,
    void* __restrict__ out, size_t out_off, int n,
    const int* __restrict__ flag)
{
  const int gw = (int)((blockIdx.x * 256 + threadIdx.x) >> 6);
  const int lane = threadIdx.x & 63;
  if (gw >= n) return;
  const unsigned short* rp = ys + (size_t)gw * 256 + lane * 4;
  float s = 0.f;
#pragma unroll
  for (int i = 0; i < 4; ++i) s += bf2f(rp[i]) * bf2f(fcw[lane * 4 + i]);
#pragma unroll
  for (int m = 32; m >= 1; m >>= 1) s += __shfl_xor(s, m, 64);
  if (lane == 0) {
    const float v = fsig(s + bf2f(fcb[0]));
    if (*flag) ((float*)out)[out_off + gw] = v;
    else       ((unsigned short*)out)[out_off + gw] = f2bf(v);
  }
}

extern "C" void kernel_launch(void* const* d_in, const int* in_sizes, int n_in,
                              void* d_out, int out_size, void* d_ws, size_t ws_size,
                              hipStream_t stream)
{
  (void)in_sizes; (void)n_in; (void)out_size;
  const int S = 4096;

  int* flag = (int*)d_ws;
  unsigned short* wbuf = (unsigned short*)((char*)d_ws + 256);
  static const int woff[14] = {0,      49152,  114688, 115200, 164352, 229888,
                               230400, 361472, 427008, 427520, 558592, 624128,
                               624640, 624896};
  const size_t wbuf_end = 256 + 1250304;  // bytes

  // Double buffers: Z0/Z1 2*C*131072 B each, ys0/ys1 2*C*32768 each
  // -> C*655360 B.
  int C = 1;
  for (int cand = 128; cand >= 1; cand >>= 1) {
    size_t need = (size_t)cand * 655360 + wbuf_end + 196608;
    if (need <= ws_size) { C = cand; break; }
  }
  unsigned short* base = (unsigned short*)((char*)d_ws + wbuf_end);
  unsigned short* Z0buf[2] = {base, base + (size_t)C * 65536};
  unsigned short* Z1buf[2] = {base + (size_t)2 * C * 65536, base + (size_t)3 * C * 65536};
  unsigned short* ys0buf[2] = {base + (size_t)4 * C * 65536,
                               base + (size_t)4 * C * 65536 + (size_t)C * 16384};
  unsigned short* ys1buf[2] = {base + (size_t)4 * C * 65536 + (size_t)2 * C * 16384,
                               base + (size_t)4 * C * 65536 + (size_t)3 * C * 16384};
  float* c0 = (float*)(base + (size_t)4 * C * 65536 + (size_t)4 * C * 16384);
  float* c1 = c0 + 16384;
  unsigned short* h0 = (unsigned short*)(c1 + 16384);
  unsigned short* h1 = h0 + 16384;

  const unsigned short* wih0f = wbuf + woff[0];
  const unsigned short* whh0f = wbuf + woff[1];
  const unsigned short* b0f   = wbuf + woff[2];
  const unsigned short* wih0b = wbuf + woff[3];
  const unsigned short* whh0b = wbuf + woff[4];
  const unsigned short* b0b   = wbuf + woff[5];
  const unsigned short* wih1f = wbuf + woff[6];
  const unsigned short* whh1f = wbuf + woff[7];
  const unsigned short* b1f   = wbuf + woff[8];
  const unsigned short* wih1b = wbuf + woff[9];
  const unsigned short* whh1b = wbuf + woff[10];
  const unsigned short* b1b   = wbuf + woff[11];
  const unsigned short* fcw   = wbuf + woff[12];
  const unsigned short* fcb   = wbuf + woff[13];

  detect_kernel<<<1, 256, 0, stream>>>((const unsigned short*)d_in[1], 49152, flag);
  convertw_kernel<<<614, 256, 0, stream>>>(
      d_in[1], d_in[2], d_in[3], d_in[4], d_in[5], d_in[6], d_in[7],
      d_in[8], d_in[9], d_in[10], d_in[11], d_in[12], d_in[13], d_in[14],
      wbuf, flag);

  const int nc = S / C;
  // prologue: gemm96 for chunk 0
  g96_kernel<<<C * 2, 512, 0, stream>>>(d_in[0], 0, flag,
                                        wih0f, wih0b, b0f, b0b, Z0buf[0]);

  const int GX = 32 + 4 * C + (C + 1) / 2;
  for (int c = 0; c <= nc + 1; ++c) {
    const int p = c & 1, pn = (c + 1) & 1;  // pn == (c-1)&1 == (c+1)&1
    rec_kernel<<<GX, 512, 0, stream>>>(
        // ctx a: L0 chunk c
        Z0buf[p], whh0f, whh0b, ys0buf[p], c0, h0, (c == 0) ? 1 : 0,
        (c <= nc - 1) ? 1 : 0,
        // ctx b: L1 chunk c-2
        Z1buf[p], whh1f, whh1b, ys1buf[p], c1, h1, (c == 2) ? 1 : 0,
        (c >= 2) ? 1 : 0,
        C,
        // embedded g96: chunk c+1
        d_in[0], (size_t)(c + 1) * C * 6144, (c <= nc - 2) ? 1 : 0, flag,
        wih0f, wih0b, b0f, b0b, Z0buf[pn],
        // embedded g256: chunk c-1 (ys0[(c-1)&1] -> Z1[(c-1)&1])
        ys0buf[pn], (c >= 1 && c <= nc) ? 1 : 0, wih1f, wih1b, b1f, b1b, Z1buf[pn],
        // embedded fc: chunk c-3 (reads ys1[(c-3)&1])
        ys1buf[pn], fcw, fcb, d_out,
        (c >= 3) ? (size_t)(c - 3) * C * 64 : 0, (c >= 3) ? C * 64 : 0);
  }
  // tail fc: chunk nc-1 (written during rec launch nc+1)
  fc_kernel<<<C * 16, 256, 0, stream>>>(ys1buf[(nc - 1) & 1], fcw, fcb, d_out,
                                        (size_t)(nc - 1) * C * 64, C * 64, flag);
}

// Round 7
// 3155.860 us; speedup vs baseline: 2.6745x; 1.5931x over previous
//
#include <hip/hip_runtime.h>
#include <stdint.h>

typedef short short8 __attribute__((ext_vector_type(8)));
typedef short short4v __attribute__((ext_vector_type(4)));
typedef float floatx4 __attribute__((ext_vector_type(4)));

#define LOG2E 1.44269504088896340736f

__device__ __forceinline__ float bf2f(unsigned short u) {
  unsigned v = ((unsigned)u) << 16;
  return __builtin_bit_cast(float, v);
}
__device__ __forceinline__ unsigned short f2bf(float f) {
  unsigned v = __builtin_bit_cast(unsigned, f);
  v += 0x7FFFu + ((v >> 16) & 1u);   // RNE
  return (unsigned short)(v >> 16);
}
__device__ __forceinline__ float fast_exp2(float x) {
#if __has_builtin(__builtin_amdgcn_exp2f)
  return __builtin_amdgcn_exp2f(x);
#else
  return exp2f(x);
#endif
}
__device__ __forceinline__ float fast_rcp(float x) {
#if __has_builtin(__builtin_amdgcn_rcpf)
  return __builtin_amdgcn_rcpf(x);
#else
  return 1.0f / x;
#endif
}
__device__ __forceinline__ float fsig(float x) {
  return fast_rcp(1.0f + fast_exp2(-LOG2E * x));
}
__device__ __forceinline__ floatx4 mfma16(short8 a, short8 b, floatx4 c) {
  return __builtin_amdgcn_mfma_f32_16x16x32_bf16(a, b, c, 0, 0, 0);
}

// ---------------------------------------------------------------------------
// Dtype detection: f32 buffers show even-u16 "exponent" >= 0xF0 often; bf16
// 0.05-scaled weights never do. flag: 1 = f32, 0 = bf16.
// ---------------------------------------------------------------------------
__global__ __launch_bounds__(256) void detect_kernel(
    const unsigned short* __restrict__ w, int n_u16, int* __restrict__ flag)
{
  __shared__ int cnt;
  if (threadIdx.x == 0) cnt = 0;
  __syncthreads();
  int local = 0;
  for (int i = threadIdx.x * 2; i < n_u16; i += 512) {
    unsigned e = (w[i] >> 7) & 0xFF;
    if (e >= 0xF0) local++;
  }
  atomicAdd(&cnt, local);
  __syncthreads();
  if (threadIdx.x == 0) *flag = (cnt > 64) ? 1 : 0;
}

// ---------------------------------------------------------------------------
// One merged kernel canonicalizing all 14 weight tensors to bf16 in ws.
// Gate-block pre-scaling: i/f/o rows (and biases) scaled by log2(e), g rows
// by 2*log2(e) -> recurrence needs only bare exp2; cell state carried in the
// 2*log2(e)*c domain. fc weights (12,13) stay unscaled.
// ---------------------------------------------------------------------------
__global__ __launch_bounds__(256) void convertw_kernel(
    const void* s0, const void* s1, const void* s2, const void* s3,
    const void* s4, const void* s5, const void* s6, const void* s7,
    const void* s8, const void* s9, const void* s10, const void* s11,
    const void* s12, const void* s13,
    unsigned short* __restrict__ wbuf, const int* __restrict__ flag)
{
  const void* srcs[14] = {s0, s1, s2, s3, s4, s5, s6, s7, s8, s9, s10, s11, s12, s13};
  const int woff[14] = {0,      49152,  114688, 115200, 164352, 229888,
                        230400, 361472, 427008, 427520, 558592, 624128,
                        624640, 624896};
  const int wlen[14] = {49152, 65536, 512, 49152, 65536, 512,
                        131072, 65536, 512, 131072, 65536, 512, 256, 1};
  const int glen[14] = {96 * 128, 128 * 128, 128, 96 * 128, 128 * 128, 128,
                        256 * 128, 128 * 128, 128, 256 * 128, 128 * 128, 128,
                        0, 0};
  int sb = 0, i = 0;
  for (i = 0; i < 14; ++i) {
    int nb = (wlen[i] + 1023) >> 10;
    if ((int)blockIdx.x < sb + nb) break;
    sb += nb;
  }
  const int base = ((int)blockIdx.x - sb) * 1024 + (int)threadIdx.x * 4;
  unsigned short* dst = wbuf + woff[i];
  const int f32 = *flag;
  const int gl = glen[i];
#pragma unroll
  for (int j = 0; j < 4; ++j) {
    const int idx = base + j;
    if (idx >= wlen[i]) break;
    float v = f32 ? ((const float*)srcs[i])[idx]
                  : bf2f(((const unsigned short*)srcs[i])[idx]);
    if (gl) {
      const int gate = (int)((unsigned)idx / (unsigned)gl);  // row >> 7
      v *= (gate == 2) ? (2.0f * LOG2E) : LOG2E;
    }
    dst[idx] = f2bf(v);
  }
}

// ---------------------------------------------------------------------------
// GEMM body for 512-thread blocks: all 8 waves stage A into LDS, then all 8
// compute 512 cols (8 waves x 64). Z output bf16, per-(t,dir,bg) slab of
// 8192 shorts laid out [bh(2)][unit(128)][q(4)][gate(4)][2 rows]:
//   offset = bh*4096 + u*32 + q*8 + g*2 + j
// so each rec thread reads ONE contiguous short8 (4 gates x 2 rows) and the
// two bh sibling blocks touch disjoint 8KB sub-slabs (round 6's layout made
// them split the same cache lines -> 2x HBM fetch).
// ---------------------------------------------------------------------------
template <int K>
__device__ __forceinline__ void gemm512_body(
    unsigned short* As, int t, int slice,
    const void* __restrict__ A, size_t a_off, int dyn,
    const int* __restrict__ flag,
    const unsigned short* __restrict__ Bf, const unsigned short* __restrict__ Bb,
    const unsigned short* __restrict__ biasf, const unsigned short* __restrict__ biasb,
    unsigned short* __restrict__ Z)
{
  constexpr int RS = K + 8;
  const int tid = threadIdx.x, lane = tid & 63;
  const int q = lane >> 4, cc = lane & 15;
  constexpr int K8 = K / 8;
  const int use32 = dyn ? *flag : 0;   // wave-uniform
  if (use32) {
    const float* Arow = (const float*)A + a_off + (size_t)t * 64 * K;
    for (int ci = tid; ci < 64 * K8; ci += 512) {
      int r_ = ci / K8, c8 = ci % K8;
      const float* p = Arow + r_ * K + c8 * 8;
      floatx4 x0 = *(const floatx4*)p;
      floatx4 x1 = *(const floatx4*)(p + 4);
      short8 s;
#pragma unroll
      for (int j = 0; j < 4; ++j) {
        s[j] = (short)f2bf(x0[j]);
        s[4 + j] = (short)f2bf(x1[j]);
      }
      *(short8*)&As[r_ * RS + c8 * 8] = s;
    }
  } else {
    const unsigned short* Arow = (const unsigned short*)A + a_off + (size_t)t * 64 * K;
    for (int ci = tid; ci < 64 * K8; ci += 512) {
      int r_ = ci / K8, c8 = ci % K8;
      *(short8*)&As[r_ * RS + c8 * 8] = *(const short8*)&Arow[r_ * K + c8 * 8];
    }
  }
  __syncthreads();
  const int w = tid >> 6;
  const unsigned short* Bp    = slice ? Bb : Bf;
  const unsigned short* biasp = slice ? biasb : biasf;
  const int cb = w * 64;
  const int dslab = slice * 4;
  floatx4 acc[4][4];
#pragma unroll
  for (int m = 0; m < 4; ++m)
#pragma unroll
    for (int n = 0; n < 4; ++n)
#pragma unroll
      for (int r = 0; r < 4; ++r) acc[m][n][r] = 0.f;
#pragma unroll
  for (int ks = 0; ks < K / 32; ++ks) {
    short8 af[4], bfr[4];
#pragma unroll
    for (int m = 0; m < 4; ++m)
      af[m] = *(const short8*)&As[(m * 16 + cc) * RS + ks * 32 + q * 8];
#pragma unroll
    for (int n = 0; n < 4; ++n)
      bfr[n] = *(const short8*)&Bp[(size_t)(cb + n * 16 + cc) * K + ks * 32 + q * 8];
#pragma unroll
    for (int m = 0; m < 4; ++m)
#pragma unroll
      for (int n = 0; n < 4; ++n)
        acc[m][n] = mfma16(af[m], bfr[n], acc[m][n]);
  }
#pragma unroll
  for (int n = 0; n < 4; ++n) {
    const int col = cb + n * 16 + cc;
    const float bv = bf2f(biasp[col]);
    const int g = col >> 7, uu = col & 127;
#pragma unroll
    for (int m = 0; m < 4; ++m) {
      const unsigned short v0 = f2bf(acc[m][n][0] + bv);
      const unsigned short v1 = f2bf(acc[m][n][1] + bv);
      const unsigned short v2 = f2bf(acc[m][n][2] + bv);
      const unsigned short v3 = f2bf(acc[m][n][3] + bv);
      const unsigned lo = (unsigned)v0 | ((unsigned)v1 << 16);
      const unsigned hi = (unsigned)v2 | ((unsigned)v3 << 16);
      unsigned short* zb =
          Z + ((size_t)t * 8 + dslab + m) * 8192 + uu * 32 + q * 8 + g * 2;
      *(unsigned*)zb = lo;              // bh=0 sub-slab (batch rows q*4+0,1)
      *(unsigned*)(zb + 4096) = hi;     // bh=1 sub-slab (batch rows q*4+2,3)
    }
  }
}

// ---------------------------------------------------------------------------
// FC body (512 threads): block idx covers timesteps idx*2 and idx*2+1.
// ---------------------------------------------------------------------------
__device__ __forceinline__ void fc512_body(
    int idx, int steps, const unsigned short* __restrict__ ys1,
    const unsigned short* __restrict__ fcw, const unsigned short* __restrict__ fcb,
    void* __restrict__ out, size_t out_off, const int* __restrict__ flag)
{
  const int tid = threadIdx.x;
  const int w = tid >> 6, lane = tid & 63;
  const int t = idx * 2 + (w >> 2);
  if (t >= steps) return;
  const int w4 = w & 3;
  const int o = lane & 15, q = lane >> 4;
  const int b = w4 * 16 + o;
  const unsigned short* rp = ys1 + ((size_t)t * 64 + b) * 256 + q * 64;
  float s = 0.f;
#pragma unroll
  for (int j = 0; j < 16; ++j) {
    short4v v = *(const short4v*)(rp + j * 4);
    const unsigned short* wp = fcw + q * 64 + j * 4;
#pragma unroll
    for (int k = 0; k < 4; ++k) s += bf2f((unsigned short)v[k]) * bf2f(wp[k]);
  }
  s += __shfl_xor(s, 16, 64);
  s += __shfl_xor(s, 32, 64);
  if (q == 0) {
    const float v = fsig(s + bf2f(fcb[0]));
    const size_t oidx = out_off + (size_t)t * 64 + b;
    if (*flag) ((float*)out)[oidx] = v;
    else       ((unsigned short*)out)[oidx] = f2bf(v);
  }
}

// ---------------------------------------------------------------------------
// Fused pipeline kernel, 512-thread blocks (8 waves, 2 waves/SIMD).
// Blocks 0..31: recurrence, batch-split 2x: block = (ctx, d, bg, bh), 8 batch
// rows each (zero extra bfrag cost - Whh shared across batch). Round-6 layout
// flaw fixed: Z slab now [bh][u][q][g][2rows] so each thread's step input is
// ONE contiguous 16B short8 load, a wave covers a contiguous 1KB, and bh
// siblings read disjoint sub-slabs (round 6: 4B scatter + every line fetched
// by both CUs -> FETCH 46.5MB and +30% period).
// Z prefetch: TWO named register sets (A/B), 2x-unrolled loop -> vmcnt wait
// lands two periods after issue.
// Blocks 32+: g96(c+1), g256(c-1), fc(c-3) workers (parity-disjoint buffers).
// ---------------------------------------------------------------------------
__global__ __attribute__((amdgpu_waves_per_eu(2, 4))) __launch_bounds__(512)
void rec_kernel(
    const unsigned short* __restrict__ Za, const unsigned short* __restrict__ whhfa,
    const unsigned short* __restrict__ whhba,
    unsigned short* __restrict__ ysa, float* __restrict__ ca,
    unsigned short* __restrict__ ha, int inita, int acta,
    const unsigned short* __restrict__ Zb, const unsigned short* __restrict__ whhfb,
    const unsigned short* __restrict__ whhbb,
    unsigned short* __restrict__ ysb, float* __restrict__ cb_,
    unsigned short* __restrict__ hb, int initb, int actb,
    int steps,
    const void* __restrict__ x, size_t x_off, int do96, const int* __restrict__ flag,
    const unsigned short* __restrict__ wih0f, const unsigned short* __restrict__ wih0b,
    const unsigned short* __restrict__ b0f, const unsigned short* __restrict__ b0b,
    unsigned short* __restrict__ Z0n,
    const unsigned short* __restrict__ ys0g, int do256,
    const unsigned short* __restrict__ wih1f, const unsigned short* __restrict__ wih1b,
    const unsigned short* __restrict__ b1f, const unsigned short* __restrict__ b1b,
    unsigned short* __restrict__ Z1n,
    const unsigned short* __restrict__ fcsrc,
    const unsigned short* __restrict__ fcw, const unsigned short* __restrict__ fcb,
    void* __restrict__ out, size_t fc_off, int fcn)
{
  __shared__ __align__(16) unsigned char smem[34816];
  const int bx = blockIdx.x;
  const int g96n = steps * 2;

  if (bx >= 32) {
    const int wi = bx - 32;
    if (wi < g96n) {                       // g96 (next chunk L0)
      if (!do96) return;
      gemm512_body<96>((unsigned short*)smem, wi >> 1, wi & 1, x, x_off, 1,
                       flag, wih0f, wih0b, b0f, b0b, Z0n);
    } else if (wi < 2 * g96n) {            // g256 (L1 chunk c-1)
      if (!do256) return;
      const int idx = wi - g96n;
      gemm512_body<256>((unsigned short*)smem, idx >> 1, idx & 1, ys0g, 0, 0,
                        flag, wih1f, wih1b, b1f, b1b, Z1n);
    } else {                               // fc (chunk c-3)
      if (fcn <= 0) return;
      fc512_body(wi - 2 * g96n, steps, fcsrc, fcw, fcb, out, fc_off, flag);
    }
    return;
  }

  // ---- recurrence path: block = (ctx, d, bg, bh) ----
  const int blk = bx;
  const int ctx = blk >> 4;
  if (ctx == 0 ? !acta : !actb) return;
  const int tid = threadIdx.x;

  const unsigned short* Z;
  const unsigned short* whhF;
  const unsigned short* whhB;
  unsigned short* ys;
  float* cst;
  unsigned short* hst;
  int init;
  if (ctx == 0) {
    Z = Za; whhF = whhfa; whhB = whhba; ys = ysa; cst = ca; hst = ha; init = inita;
  } else {
    Z = Zb; whhF = whhfb; whhB = whhbb; ys = ysb; cst = cb_; hst = hb; init = initb;
  }
  const int d = (blk >> 3) & 1, bg = (blk >> 1) & 3, bh = blk & 1;
  const unsigned short* whh = d ? whhB : whhF;

  unsigned short (*hbuf)[16][136] = (unsigned short(*)[16][136])smem;

  const int w = tid >> 6, lane = tid & 63, q = lane >> 4, cc = lane & 15;
  const int u = w * 16 + cc;
  const int rb = bh * 2;             // acc register rows rb, rb+1 are ours

  // Whh as MFMA B-fragments, register-resident (64 regs -> AGPR file).
  short8 bfrag[4][4];
#pragma unroll
  for (int g = 0; g < 4; ++g)
#pragma unroll
    for (int k = 0; k < 4; ++k)
      bfrag[g][k] = *(const short8*)(whh + (size_t)(g * 128 + u) * 128 + k * 32 + q * 8);

  // drain/load lane mapping: 8 owned rows, physical row = q'*4 + bh*2 + j
  const int rowp = tid >> 6;                         // 0..7
  const int prow = (rowp >> 1) * 4 + bh * 2 + (rowp & 1);
  const int col2 = (tid & 63) * 2;                   // 0..126 even

  // zero BOTH hbuf buffers (foreign-bh rows must read as 0 forever)
  {
    unsigned* hz = (unsigned*)smem;
    for (int i = tid; i < 2 * 16 * 68; i += 512) hz[i] = 0u;
  }
  __syncthreads();

  float creg[2];                     // 2 cell rows/thread, 2*log2(e)*c domain
  if (init) {
#pragma unroll
    for (int j = 0; j < 2; ++j) creg[j] = 0.f;
  } else {
#pragma unroll
    for (int j = 0; j < 2; ++j)
      creg[j] = cst[(size_t)(d * 64 + bg * 16 + q * 4 + rb + j) * 128 + u];
    *(unsigned*)&hbuf[0][prow][col2] =
        *(const unsigned*)(hst + (size_t)(d * 64 + bg * 16 + prow) * 128 + col2);
  }
  __syncthreads();

  // per-thread z: ONE contiguous short8 = 4 gates x 2 rows
  const size_t zoff =
      (size_t)(d * 4 + bg) * 8192 + (size_t)bh * 4096 + u * 32 + q * 8;
  const unsigned short* zpA = Z + zoff;             // even-step addresses
  const unsigned short* zpB = Z + zoff + 65536;     // odd-step addresses
  short8 zA = *(const short8*)zpA;
  short8 zB = *(const short8*)zpB;
  zpA += 131072;
  zpB += 131072;

  unsigned short* ysb_ = ys + (size_t)(bg * 16 + prow) * 256 + d * 128 + col2;

  // one timestep; cur/nxt compile-time at each call site.
  auto half_step = [&](short8& zs, const unsigned short*& zp, int t,
                       int cur, int nxt) __attribute__((always_inline)) {
    floatx4 acc[4];
    if (bh == 0) {                   // block-uniform branch
#pragma unroll
      for (int g = 0; g < 4; ++g) {
        acc[g][0] = bf2f((unsigned short)zs[g * 2]);
        acc[g][1] = bf2f((unsigned short)zs[g * 2 + 1]);
        acc[g][2] = 0.f; acc[g][3] = 0.f;
      }
    } else {
#pragma unroll
      for (int g = 0; g < 4; ++g) {
        acc[g][0] = 0.f; acc[g][1] = 0.f;
        acc[g][2] = bf2f((unsigned short)zs[g * 2]);
        acc[g][3] = bf2f((unsigned short)zs[g * 2 + 1]);
      }
    }
    // prefetch this set's t+2 data; vmcnt wait is two periods away
    zs = *(const short8*)zp;
    zp += 131072;

    short8 af[4];
#pragma unroll
    for (int k = 0; k < 4; ++k)
      af[k] = *(const short8*)&hbuf[cur][cc][k * 32 + q * 8];
#pragma unroll
    for (int g = 0; g < 4; ++g)
#pragma unroll
      for (int k = 0; k < 4; ++k)
        acc[g] = mfma16(af[k], bfrag[g][k], acc[g]);

    // fused pointwise on the 2 owned rows: 5 exp2 + 2 rcp per row.
#pragma unroll
    for (int j = 0; j < 2; ++j) {
      const int rr = rb + j;
      const float ei = fast_exp2(acc[0][rr]);
      const float ef = fast_exp2(acc[1][rr]);
      const float eg = fast_exp2(acc[2][rr]);
      const float a1 = 1.0f + ei, a2 = 1.0f + eg, a3 = 1.0f + ef;
      const float p12 = a1 * a2;
      const float rD = fast_rcp(p12 * a3);
      const float t2 = __builtin_fmaf(eg, 2.0f * LOG2E, -2.0f * LOG2E);
      const float it2 = ei * t2 * (a3 * rD);       // 2L * sig(i)*tanh(g)
      const float sf = ef * (p12 * rD);            // sig(f)
      const float cs = __builtin_fmaf(sf, creg[j], it2);
      creg[j] = cs;
      const float eo = fast_exp2(acc[3][rr]);
      const float ec = fast_exp2(fminf(cs, 88.0f));  // e^{2c}
      const float h = eo * (ec - 1.0f) * fast_rcp((1.0f + eo) * (1.0f + ec));
      hbuf[nxt][q * 4 + rr][u] = f2bf(h);
    }
    // LDS-only barrier: drain ds ops; z prefetch (vmcnt) stays in flight
    asm volatile("s_waitcnt lgkmcnt(0)\n\ts_barrier" ::: "memory");
    // drain ys rows t (this block's 8 rows) - fire-and-forget store
    unsigned hv = *(const unsigned*)&hbuf[nxt][prow][col2];
    *(unsigned*)(ysb_ + (size_t)t * 16384) = hv;
  };

  int t = 0;
  for (; t + 2 <= steps; t += 2) {
    half_step(zA, zpA, t, 0, 1);
    half_step(zB, zpB, t + 1, 1, 0);
  }
  if (t < steps)                      // odd-step tail (C=1 fallback only)
    half_step(zA, zpA, t, 0, 1);

#pragma unroll
  for (int j = 0; j < 2; ++j)
    cst[(size_t)(d * 64 + bg * 16 + q * 4 + rb + j) * 128 + u] = creg[j];
  const int fin = steps & 1;
  *(unsigned*)(hst + (size_t)(d * 64 + bg * 16 + prow) * 128 + col2) =
      *(const unsigned*)&hbuf[fin][prow][col2];
}

// ---------------------------------------------------------------------------
// Standalone gemm96 (chunk 0 prologue). Grid 2C x 512.
// ---------------------------------------------------------------------------
__global__ __attribute__((amdgpu_waves_per_eu(2, 4))) __launch_bounds__(512)
void g96_kernel(
    const void* __restrict__ x, size_t x_off, const int* __restrict__ flag,
    const unsigned short* __restrict__ Bf, const unsigned short* __restrict__ Bb,
    const unsigned short* __restrict__ biasf, const unsigned short* __restrict__ biasb,
    unsigned short* __restrict__ Z)
{
  __shared__ __align__(16) unsigned short As[64 * 104];
  gemm512_body<96>(As, blockIdx.x >> 1, blockIdx.x & 1, x, x_off, 1, flag,
                   Bf, Bb, biasf, biasb, Z);
}

// ---------------------------------------------------------------------------
// Standalone FC (final chunk). One wave per (t,b).
// ---------------------------------------------------------------------------
__global__ __launch_bounds__(256) void fc_kernel(
    const unsigned short* __restrict__ ys,
    const unsigned short* __restrict__ fcw,
    const unsigned short* __restrict__ fcb,
    void* __restrict__ out, size_t out_off, int n,
    const int* __restrict__ flag)
{
  const int gw = (int)((blockIdx.x * 256 + threadIdx.x) >> 6);
  const int lane = threadIdx.x & 63;
  if (gw >= n) return;
  const unsigned short* rp = ys + (size_t)gw * 256 + lane * 4;
  float s = 0.f;
#pragma unroll
  for (int i = 0; i < 4; ++i) s += bf2f(rp[i]) * bf2f(fcw[lane * 4 + i]);
#pragma unroll
  for (int m = 32; m >= 1; m >>= 1) s += __shfl_xor(s, m, 64);
  if (lane == 0) {
    const float v = fsig(s + bf2f(fcb[0]));
    if (*flag) ((float*)out)[out_off + gw] = v;
    else       ((unsigned short*)out)[out_off + gw] = f2bf(v);
  }
}

extern "C" void kernel_launch(void* const* d_in, const int* in_sizes, int n_in,
                              void* d_out, int out_size, void* d_ws, size_t ws_size,
                              hipStream_t stream)
{
  (void)in_sizes; (void)n_in; (void)out_size;
  const int S = 4096;

  int* flag = (int*)d_ws;
  unsigned short* wbuf = (unsigned short*)((char*)d_ws + 256);
  static const int woff[14] = {0,      49152,  114688, 115200, 164352, 229888,
                               230400, 361472, 427008, 427520, 558592, 624128,
                               624640, 624896};
  const size_t wbuf_end = 256 + 1250304;  // bytes

  // Double buffers: Z0/Z1 2*C*131072 B each, ys0/ys1 2*C*32768 each
  // -> C*655360 B.
  int C = 1;
  for (int cand = 128; cand >= 1; cand >>= 1) {
    size_t need = (size_t)cand * 655360 + wbuf_end + 196608;
    if (need <= ws_size) { C = cand; break; }
  }
  unsigned short* base = (unsigned short*)((char*)d_ws + wbuf_end);
  unsigned short* Z0buf[2] = {base, base + (size_t)C * 65536};
  unsigned short* Z1buf[2] = {base + (size_t)2 * C * 65536, base + (size_t)3 * C * 65536};
  unsigned short* ys0buf[2] = {base + (size_t)4 * C * 65536,
                               base + (size_t)4 * C * 65536 + (size_t)C * 16384};
  unsigned short* ys1buf[2] = {base + (size_t)4 * C * 65536 + (size_t)2 * C * 16384,
                               base + (size_t)4 * C * 65536 + (size_t)3 * C * 16384};
  float* c0 = (float*)(base + (size_t)4 * C * 65536 + (size_t)4 * C * 16384);
  float* c1 = c0 + 16384;
  unsigned short* h0 = (unsigned short*)(c1 + 16384);
  unsigned short* h1 = h0 + 16384;

  const unsigned short* wih0f = wbuf + woff[0];
  const unsigned short* whh0f = wbuf + woff[1];
  const unsigned short* b0f   = wbuf + woff[2];
  const unsigned short* wih0b = wbuf + woff[3];
  const unsigned short* whh0b = wbuf + woff[4];
  const unsigned short* b0b   = wbuf + woff[5];
  const unsigned short* wih1f = wbuf + woff[6];
  const unsigned short* whh1f = wbuf + woff[7];
  const unsigned short* b1f   = wbuf + woff[8];
  const unsigned short* wih1b = wbuf + woff[9];
  const unsigned short* whh1b = wbuf + woff[10];
  const unsigned short* b1b   = wbuf + woff[11];
  const unsigned short* fcw   = wbuf + woff[12];
  const unsigned short* fcb   = wbuf + woff[13];

  detect_kernel<<<1, 256, 0, stream>>>((const unsigned short*)d_in[1], 49152, flag);
  convertw_kernel<<<614, 256, 0, stream>>>(
      d_in[1], d_in[2], d_in[3], d_in[4], d_in[5], d_in[6], d_in[7],
      d_in[8], d_in[9], d_in[10], d_in[11], d_in[12], d_in[13], d_in[14],
      wbuf, flag);

  const int nc = S / C;
  // prologue: gemm96 for chunk 0
  g96_kernel<<<C * 2, 512, 0, stream>>>(d_in[0], 0, flag,
                                        wih0f, wih0b, b0f, b0b, Z0buf[0]);

  const int GX = 32 + 4 * C + (C + 1) / 2;
  for (int c = 0; c <= nc + 1; ++c) {
    const int p = c & 1, pn = (c + 1) & 1;  // pn == (c-1)&1 == (c+1)&1
    rec_kernel<<<GX, 512, 0, stream>>>(
        // ctx a: L0 chunk c
        Z0buf[p], whh0f, whh0b, ys0buf[p], c0, h0, (c == 0) ? 1 : 0,
        (c <= nc - 1) ? 1 : 0,
        // ctx b: L1 chunk c-2
        Z1buf[p], whh1f, whh1b, ys1buf[p], c1, h1, (c == 2) ? 1 : 0,
        (c >= 2) ? 1 : 0,
        C,
        // embedded g96: chunk c+1
        d_in[0], (size_t)(c + 1) * C * 6144, (c <= nc - 2) ? 1 : 0, flag,
        wih0f, wih0b, b0f, b0b, Z0buf[pn],
        // embedded g256: chunk c-1 (ys0[(c-1)&1] -> Z1[(c-1)&1])
        ys0buf[pn], (c >= 1 && c <= nc) ? 1 : 0, wih1f, wih1b, b1f, b1b, Z1buf[pn],
        // embedded fc: chunk c-3 (reads ys1[(c-3)&1])
        ys1buf[pn], fcw, fcb, d_out,
        (c >= 3) ? (size_t)(c - 3) * C * 64 : 0, (c >= 3) ? C * 64 : 0);
  }
  // tail fc: chunk nc-1 (written during rec launch nc+1)
  fc_kernel<<<C * 16, 256, 0, stream>>>(ys1buf[(nc - 1) & 1], fcw, fcb, d_out,
                                        (size_t)(nc - 1) * C * 64, C * 64, flag);
}

// Round 8
// 2503.073 us; speedup vs baseline: 3.3720x; 1.2608x over previous
//
#include <hip/hip_runtime.h>
#include <stdint.h>

typedef short short8 __attribute__((ext_vector_type(8)));
typedef short short4v __attribute__((ext_vector_type(4)));
typedef float floatx4 __attribute__((ext_vector_type(4)));

#define LOG2E 1.44269504088896340736f

template <int N> struct IC { static constexpr int value = N; };

__device__ __forceinline__ float bf2f(unsigned short u) {
  unsigned v = ((unsigned)u) << 16;
  return __builtin_bit_cast(float, v);
}
__device__ __forceinline__ unsigned short f2bf(float f) {
  unsigned v = __builtin_bit_cast(unsigned, f);
  v += 0x7FFFu + ((v >> 16) & 1u);   // RNE
  return (unsigned short)(v >> 16);
}
__device__ __forceinline__ float fast_exp2(float x) {
#if __has_builtin(__builtin_amdgcn_exp2f)
  return __builtin_amdgcn_exp2f(x);
#else
  return exp2f(x);
#endif
}
__device__ __forceinline__ float fast_rcp(float x) {
#if __has_builtin(__builtin_amdgcn_rcpf)
  return __builtin_amdgcn_rcpf(x);
#else
  return 1.0f / x;
#endif
}
__device__ __forceinline__ float fsig(float x) {
  return fast_rcp(1.0f + fast_exp2(-LOG2E * x));
}
__device__ __forceinline__ floatx4 mfma16(short8 a, short8 b, floatx4 c) {
  return __builtin_amdgcn_mfma_f32_16x16x32_bf16(a, b, c, 0, 0, 0);
}

// ---------------------------------------------------------------------------
// Dtype detection: f32 buffers show even-u16 "exponent" >= 0xF0 often; bf16
// 0.05-scaled weights never do. flag: 1 = f32, 0 = bf16.
// ---------------------------------------------------------------------------
__global__ __launch_bounds__(256) void detect_kernel(
    const unsigned short* __restrict__ w, int n_u16, int* __restrict__ flag)
{
  __shared__ int cnt;
  if (threadIdx.x == 0) cnt = 0;
  __syncthreads();
  int local = 0;
  for (int i = threadIdx.x * 2; i < n_u16; i += 512) {
    unsigned e = (w[i] >> 7) & 0xFF;
    if (e >= 0xF0) local++;
  }
  atomicAdd(&cnt, local);
  __syncthreads();
  if (threadIdx.x == 0) *flag = (cnt > 64) ? 1 : 0;
}

// ---------------------------------------------------------------------------
// One merged kernel canonicalizing all 14 weight tensors to bf16 in ws.
// Gate-block pre-scaling: i/f/o rows (and biases) scaled by log2(e), g rows
// by 2*log2(e) -> recurrence needs only bare exp2; cell state carried in the
// 2*log2(e)*c domain. fc weights (12,13) stay unscaled.
// ---------------------------------------------------------------------------
__global__ __launch_bounds__(256) void convertw_kernel(
    const void* s0, const void* s1, const void* s2, const void* s3,
    const void* s4, const void* s5, const void* s6, const void* s7,
    const void* s8, const void* s9, const void* s10, const void* s11,
    const void* s12, const void* s13,
    unsigned short* __restrict__ wbuf, const int* __restrict__ flag)
{
  const void* srcs[14] = {s0, s1, s2, s3, s4, s5, s6, s7, s8, s9, s10, s11, s12, s13};
  const int woff[14] = {0,      49152,  114688, 115200, 164352, 229888,
                        230400, 361472, 427008, 427520, 558592, 624128,
                        624640, 624896};
  const int wlen[14] = {49152, 65536, 512, 49152, 65536, 512,
                        131072, 65536, 512, 131072, 65536, 512, 256, 1};
  const int glen[14] = {96 * 128, 128 * 128, 128, 96 * 128, 128 * 128, 128,
                        256 * 128, 128 * 128, 128, 256 * 128, 128 * 128, 128,
                        0, 0};
  int sb = 0, i = 0;
  for (i = 0; i < 14; ++i) {
    int nb = (wlen[i] + 1023) >> 10;
    if ((int)blockIdx.x < sb + nb) break;
    sb += nb;
  }
  const int base = ((int)blockIdx.x - sb) * 1024 + (int)threadIdx.x * 4;
  unsigned short* dst = wbuf + woff[i];
  const int f32 = *flag;
  const int gl = glen[i];
#pragma unroll
  for (int j = 0; j < 4; ++j) {
    const int idx = base + j;
    if (idx >= wlen[i]) break;
    float v = f32 ? ((const float*)srcs[i])[idx]
                  : bf2f(((const unsigned short*)srcs[i])[idx]);
    if (gl) {
      const int gate = (int)((unsigned)idx / (unsigned)gl);  // row >> 7
      v *= (gate == 2) ? (2.0f * LOG2E) : LOG2E;
    }
    dst[idx] = f2bf(v);
  }
}

// ---------------------------------------------------------------------------
// GEMM body for 512-thread blocks: all 8 waves stage A into LDS, then all 8
// compute 512 cols (8 waves x 64). Z output bf16, per-(t,dir,bg) slab of
// 8192 shorts laid out [bh(4)][unit(128)][q(4)][gate(4)]:
//   offset = bh*2048 + u*16 + q*4 + g
// so each rec thread reads ONE contiguous 8B quad (4 gates x 1 row), a wave
// covers a contiguous 512B, and the four bh sibling blocks touch disjoint
// 4KB sub-slabs (round-6 lesson: sharing cache lines across sibling CUs
// doubles HBM fetch).
// ---------------------------------------------------------------------------
template <int K>
__device__ __forceinline__ void gemm512_body(
    unsigned short* As, int t, int slice,
    const void* __restrict__ A, size_t a_off, int dyn,
    const int* __restrict__ flag,
    const unsigned short* __restrict__ Bf, const unsigned short* __restrict__ Bb,
    const unsigned short* __restrict__ biasf, const unsigned short* __restrict__ biasb,
    unsigned short* __restrict__ Z)
{
  constexpr int RS = K + 8;
  const int tid = threadIdx.x, lane = tid & 63;
  const int q = lane >> 4, cc = lane & 15;
  constexpr int K8 = K / 8;
  const int use32 = dyn ? *flag : 0;   // wave-uniform
  if (use32) {
    const float* Arow = (const float*)A + a_off + (size_t)t * 64 * K;
    for (int ci = tid; ci < 64 * K8; ci += 512) {
      int r_ = ci / K8, c8 = ci % K8;
      const float* p = Arow + r_ * K + c8 * 8;
      floatx4 x0 = *(const floatx4*)p;
      floatx4 x1 = *(const floatx4*)(p + 4);
      short8 s;
#pragma unroll
      for (int j = 0; j < 4; ++j) {
        s[j] = (short)f2bf(x0[j]);
        s[4 + j] = (short)f2bf(x1[j]);
      }
      *(short8*)&As[r_ * RS + c8 * 8] = s;
    }
  } else {
    const unsigned short* Arow = (const unsigned short*)A + a_off + (size_t)t * 64 * K;
    for (int ci = tid; ci < 64 * K8; ci += 512) {
      int r_ = ci / K8, c8 = ci % K8;
      *(short8*)&As[r_ * RS + c8 * 8] = *(const short8*)&Arow[r_ * K + c8 * 8];
    }
  }
  __syncthreads();
  const int w = tid >> 6;
  const unsigned short* Bp    = slice ? Bb : Bf;
  const unsigned short* biasp = slice ? biasb : biasf;
  const int cb = w * 64;
  const int dslab = slice * 4;
  floatx4 acc[4][4];
#pragma unroll
  for (int m = 0; m < 4; ++m)
#pragma unroll
    for (int n = 0; n < 4; ++n)
#pragma unroll
      for (int r = 0; r < 4; ++r) acc[m][n][r] = 0.f;
#pragma unroll
  for (int ks = 0; ks < K / 32; ++ks) {
    short8 af[4], bfr[4];
#pragma unroll
    for (int m = 0; m < 4; ++m)
      af[m] = *(const short8*)&As[(m * 16 + cc) * RS + ks * 32 + q * 8];
#pragma unroll
    for (int n = 0; n < 4; ++n)
      bfr[n] = *(const short8*)&Bp[(size_t)(cb + n * 16 + cc) * K + ks * 32 + q * 8];
#pragma unroll
    for (int m = 0; m < 4; ++m)
#pragma unroll
      for (int n = 0; n < 4; ++n)
        acc[m][n] = mfma16(af[m], bfr[n], acc[m][n]);
  }
#pragma unroll
  for (int n = 0; n < 4; ++n) {
    const int col = cb + n * 16 + cc;
    const float bv = bf2f(biasp[col]);
    const int g = col >> 7, uu = col & 127;
#pragma unroll
    for (int m = 0; m < 4; ++m) {
      unsigned short* zb =
          Z + ((size_t)t * 8 + dslab + m) * 8192 + uu * 16 + q * 4 + g;
#pragma unroll
      for (int r = 0; r < 4; ++r)
        zb[r * 2048] = f2bf(acc[m][n][r] + bv);   // bh=r sub-slab
    }
  }
}

// ---------------------------------------------------------------------------
// FC body (512 threads): block idx covers timesteps idx*2 and idx*2+1.
// ---------------------------------------------------------------------------
__device__ __forceinline__ void fc512_body(
    int idx, int steps, const unsigned short* __restrict__ ys1,
    const unsigned short* __restrict__ fcw, const unsigned short* __restrict__ fcb,
    void* __restrict__ out, size_t out_off, const int* __restrict__ flag)
{
  const int tid = threadIdx.x;
  const int w = tid >> 6, lane = tid & 63;
  const int t = idx * 2 + (w >> 2);
  if (t >= steps) return;
  const int w4 = w & 3;
  const int o = lane & 15, q = lane >> 4;
  const int b = w4 * 16 + o;
  const unsigned short* rp = ys1 + ((size_t)t * 64 + b) * 256 + q * 64;
  float s = 0.f;
#pragma unroll
  for (int j = 0; j < 16; ++j) {
    short4v v = *(const short4v*)(rp + j * 4);
    const unsigned short* wp = fcw + q * 64 + j * 4;
#pragma unroll
    for (int k = 0; k < 4; ++k) s += bf2f((unsigned short)v[k]) * bf2f(wp[k]);
  }
  s += __shfl_xor(s, 16, 64);
  s += __shfl_xor(s, 32, 64);
  if (q == 0) {
    const float v = fsig(s + bf2f(fcb[0]));
    const size_t oidx = out_off + (size_t)t * 64 + b;
    if (*flag) ((float*)out)[oidx] = v;
    else       ((unsigned short*)out)[oidx] = f2bf(v);
  }
}

// ---------------------------------------------------------------------------
// Fused pipeline kernel, 512-thread blocks (8 waves, 2 waves/SIMD).
// Blocks 0..63: recurrence, batch-split 4x: block = (ctx, d, bg, bh),
// bh in {0..3}, 4 batch rows per block, ONE row per thread. Rationale: round
// 7 (2x split, fixed layout) gave -19% and chip-VALUBusy implies rec CUs'
// VALU pipe ~80% busy (exp2/rcp are quarter-rate on the VALU pipe), so the
// per-wave pointwise issue is still the dominant scaling term. 4x split
// halves it again (7 trans, ~22 VALU per thread) at zero extra bfrag cost.
// Register indexing kept fully STATIC via switch(bh) -> templated loop
// (runtime-indexed ext_vector goes to scratch, round-3/4 lesson catalog).
// Z slab [bh(4)][u][q][g]: thread reads one contiguous 8B quad; wave reads
// contiguous 512B; bh siblings disjoint 4KB sub-slabs.
// Z prefetch: TWO named register sets (A/B), 2x-unrolled loop -> vmcnt wait
// lands two periods after issue.
// Blocks 64+: g96(c+1), g256(c-1), fc(c-3) workers (parity-disjoint buffers).
// ---------------------------------------------------------------------------
__global__ __attribute__((amdgpu_waves_per_eu(2, 4))) __launch_bounds__(512)
void rec_kernel(
    const unsigned short* __restrict__ Za, const unsigned short* __restrict__ whhfa,
    const unsigned short* __restrict__ whhba,
    unsigned short* __restrict__ ysa, float* __restrict__ ca,
    unsigned short* __restrict__ ha, int inita, int acta,
    const unsigned short* __restrict__ Zb, const unsigned short* __restrict__ whhfb,
    const unsigned short* __restrict__ whhbb,
    unsigned short* __restrict__ ysb, float* __restrict__ cb_,
    unsigned short* __restrict__ hb, int initb, int actb,
    int steps,
    const void* __restrict__ x, size_t x_off, int do96, const int* __restrict__ flag,
    const unsigned short* __restrict__ wih0f, const unsigned short* __restrict__ wih0b,
    const unsigned short* __restrict__ b0f, const unsigned short* __restrict__ b0b,
    unsigned short* __restrict__ Z0n,
    const unsigned short* __restrict__ ys0g, int do256,
    const unsigned short* __restrict__ wih1f, const unsigned short* __restrict__ wih1b,
    const unsigned short* __restrict__ b1f, const unsigned short* __restrict__ b1b,
    unsigned short* __restrict__ Z1n,
    const unsigned short* __restrict__ fcsrc,
    const unsigned short* __restrict__ fcw, const unsigned short* __restrict__ fcb,
    void* __restrict__ out, size_t fc_off, int fcn)
{
  __shared__ __align__(16) unsigned char smem[34816];
  const int bx = blockIdx.x;
  const int g96n = steps * 2;

  if (bx >= 64) {
    const int wi = bx - 64;
    if (wi < g96n) {                       // g96 (next chunk L0)
      if (!do96) return;
      gemm512_body<96>((unsigned short*)smem, wi >> 1, wi & 1, x, x_off, 1,
                       flag, wih0f, wih0b, b0f, b0b, Z0n);
    } else if (wi < 2 * g96n) {            // g256 (L1 chunk c-1)
      if (!do256) return;
      const int idx = wi - g96n;
      gemm512_body<256>((unsigned short*)smem, idx >> 1, idx & 1, ys0g, 0, 0,
                        flag, wih1f, wih1b, b1f, b1b, Z1n);
    } else {                               // fc (chunk c-3)
      if (fcn <= 0) return;
      fc512_body(wi - 2 * g96n, steps, fcsrc, fcw, fcb, out, fc_off, flag);
    }
    return;
  }

  // ---- recurrence path: block = (ctx, d, bg, bh) ----
  const int blk = bx;
  const int ctx = blk >> 5;
  if (ctx == 0 ? !acta : !actb) return;
  const int tid = threadIdx.x;

  const unsigned short* Z;
  const unsigned short* whhF;
  const unsigned short* whhB;
  unsigned short* ys;
  float* cst;
  unsigned short* hst;
  int init;
  if (ctx == 0) {
    Z = Za; whhF = whhfa; whhB = whhba; ys = ysa; cst = ca; hst = ha; init = inita;
  } else {
    Z = Zb; whhF = whhfb; whhB = whhbb; ys = ysb; cst = cb_; hst = hb; init = initb;
  }
  const int d = (blk >> 4) & 1, bg = (blk >> 2) & 3, bh = blk & 3;
  const unsigned short* whh = d ? whhB : whhF;

  unsigned short (*hbuf)[16][136] = (unsigned short(*)[16][136])smem;

  const int w = tid >> 6, lane = tid & 63, q = lane >> 4, cc = lane & 15;
  const int u = w * 16 + cc;

  // Whh as MFMA B-fragments, register-resident (64 regs -> AGPR file).
  short8 bfrag[4][4];
#pragma unroll
  for (int g = 0; g < 4; ++g)
#pragma unroll
    for (int k = 0; k < 4; ++k)
      bfrag[g][k] = *(const short8*)(whh + (size_t)(g * 128 + u) * 128 + k * 32 + q * 8);

  // drain/load lane mapping: 4 owned rows (r%4==bh), 1 elem/thread
  const int prow = (tid >> 7) * 4 + bh;              // physical batch row
  const int pcol = tid & 127;                        // unit column

  // zero BOTH hbuf buffers (foreign-bh rows must read as 0 forever)
  {
    unsigned* hz = (unsigned*)smem;
    for (int i = tid; i < 2 * 16 * 68; i += 512) hz[i] = 0u;
  }
  __syncthreads();

  float creg;                        // 1 cell row/thread, 2*log2(e)*c domain
  if (init) {
    creg = 0.f;
  } else {
    creg = cst[(size_t)(d * 64 + bg * 16 + q * 4 + bh) * 128 + u];
    hbuf[0][prow][pcol] = hst[(size_t)(d * 64 + bg * 16 + prow) * 128 + pcol];
  }
  __syncthreads();

  // per-thread z: ONE contiguous 8B quad = 4 gates x 1 row
  const size_t zoff =
      (size_t)(d * 4 + bg) * 8192 + (size_t)bh * 2048 + u * 16 + q * 4;
  const unsigned short* zpA = Z + zoff;             // even-step addresses
  const unsigned short* zpB = Z + zoff + 65536;     // odd-step addresses
  short4v zA = *(const short4v*)zpA;
  short4v zB = *(const short4v*)zpB;
  zpA += 131072;
  zpB += 131072;

  unsigned short* ysb_ = ys + (size_t)(bg * 16 + prow) * 256 + d * 128 + pcol;

  // one timestep; BH compile-time via IC dispatch, cur/nxt compile-time.
  auto half_step = [&](auto bhc, short4v& zs, const unsigned short*& zp, int t,
                       int cur, int nxt) __attribute__((always_inline)) {
    constexpr int BH = decltype(bhc)::value;
    floatx4 acc[4];
#pragma unroll
    for (int g = 0; g < 4; ++g)
#pragma unroll
      for (int r = 0; r < 4; ++r)
        acc[g][r] = (r == BH) ? bf2f((unsigned short)zs[g]) : 0.f;
    // prefetch this set's t+2 data; vmcnt wait is two periods away
    zs = *(const short4v*)zp;
    zp += 131072;

    short8 af[4];
#pragma unroll
    for (int k = 0; k < 4; ++k)
      af[k] = *(const short8*)&hbuf[cur][cc][k * 32 + q * 8];
#pragma unroll
    for (int g = 0; g < 4; ++g)
#pragma unroll
      for (int k = 0; k < 4; ++k)
        acc[g] = mfma16(af[k], bfrag[g][k], acc[g]);

    // fused pointwise on the 1 owned row: 5 exp2 + 2 rcp.
    {
      const float ei = fast_exp2(acc[0][BH]);
      const float ef = fast_exp2(acc[1][BH]);
      const float eg = fast_exp2(acc[2][BH]);
      const float a1 = 1.0f + ei, a2 = 1.0f + eg, a3 = 1.0f + ef;
      const float p12 = a1 * a2;
      const float rD = fast_rcp(p12 * a3);
      const float t2 = __builtin_fmaf(eg, 2.0f * LOG2E, -2.0f * LOG2E);
      const float it2 = ei * t2 * (a3 * rD);       // 2L * sig(i)*tanh(g)
      const float sf = ef * (p12 * rD);            // sig(f)
      const float cs = __builtin_fmaf(sf, creg, it2);
      creg = cs;
      const float eo = fast_exp2(acc[3][BH]);
      const float ec = fast_exp2(fminf(cs, 88.0f));  // e^{2c}
      const float h = eo * (ec - 1.0f) * fast_rcp((1.0f + eo) * (1.0f + ec));
      hbuf[nxt][q * 4 + BH][u] = f2bf(h);
    }
    // LDS-only barrier: drain ds ops; z prefetch (vmcnt) stays in flight
    asm volatile("s_waitcnt lgkmcnt(0)\n\ts_barrier" ::: "memory");
    // drain ys rows t (this block's 4 rows) - fire-and-forget store
    ysb_[(size_t)t * 16384] = hbuf[nxt][prow][pcol];
  };

  auto run = [&](auto bhc) __attribute__((always_inline)) {
    int t = 0;
    for (; t + 2 <= steps; t += 2) {
      half_step(bhc, zA, zpA, t, 0, 1);
      half_step(bhc, zB, zpB, t + 1, 1, 0);
    }
    if (t < steps)                    // odd-step tail (C=1 fallback only)
      half_step(bhc, zA, zpA, t, 0, 1);
  };
  switch (bh) {
    case 0: run(IC<0>{}); break;
    case 1: run(IC<1>{}); break;
    case 2: run(IC<2>{}); break;
    default: run(IC<3>{}); break;
  }

  cst[(size_t)(d * 64 + bg * 16 + q * 4 + bh) * 128 + u] = creg;
  const int fin = steps & 1;
  hst[(size_t)(d * 64 + bg * 16 + prow) * 128 + pcol] = hbuf[fin][prow][pcol];
}

// ---------------------------------------------------------------------------
// Standalone gemm96 (chunk 0 prologue). Grid 2C x 512.
// ---------------------------------------------------------------------------
__global__ __attribute__((amdgpu_waves_per_eu(2, 4))) __launch_bounds__(512)
void g96_kernel(
    const void* __restrict__ x, size_t x_off, const int* __restrict__ flag,
    const unsigned short* __restrict__ Bf, const unsigned short* __restrict__ Bb,
    const unsigned short* __restrict__ biasf, const unsigned short* __restrict__ biasb,
    unsigned short* __restrict__ Z)
{
  __shared__ __align__(16) unsigned short As[64 * 104];
  gemm512_body<96>(As, blockIdx.x >> 1, blockIdx.x & 1, x, x_off, 1, flag,
                   Bf, Bb, biasf, biasb, Z);
}

// ---------------------------------------------------------------------------
// Standalone FC (final chunk). One wave per (t,b).
// ---------------------------------------------------------------------------
__global__ __launch_bounds__(256) void fc_kernel(
    const unsigned short* __restrict__ ys,
    const unsigned short* __restrict__ fcw,
    const unsigned short* __restrict__ fcb,
    void* __restrict__ out, size_t out_off, int n,
    const int* __restrict__ flag)
{
  const int gw = (int)((blockIdx.x * 256 + threadIdx.x) >> 6);
  const int lane = threadIdx.x & 63;
  if (gw >= n) return;
  const unsigned short* rp = ys + (size_t)gw * 256 + lane * 4;
  float s = 0.f;
#pragma unroll
  for (int i = 0; i < 4; ++i) s += bf2f(rp[i]) * bf2f(fcw[lane * 4 + i]);
#pragma unroll
  for (int m = 32; m >= 1; m >>= 1) s += __shfl_xor(s, m, 64);
  if (lane == 0) {
    const float v = fsig(s + bf2f(fcb[0]));
    if (*flag) ((float*)out)[out_off + gw] = v;
    else       ((unsigned short*)out)[out_off + gw] = f2bf(v);
  }
}

extern "C" void kernel_launch(void* const* d_in, const int* in_sizes, int n_in,
                              void* d_out, int out_size, void* d_ws, size_t ws_size,
                              hipStream_t stream)
{
  (void)in_sizes; (void)n_in; (void)out_size;
  const int S = 4096;

  int* flag = (int*)d_ws;
  unsigned short* wbuf = (unsigned short*)((char*)d_ws + 256);
  static const int woff[14] = {0,      49152,  114688, 115200, 164352, 229888,
                               230400, 361472, 427008, 427520, 558592, 624128,
                               624640, 624896};
  const size_t wbuf_end = 256 + 1250304;  // bytes

  // Double buffers: Z0/Z1 2*C*131072 B each, ys0/ys1 2*C*32768 each
  // -> C*655360 B.
  int C = 1;
  for (int cand = 128; cand >= 1; cand >>= 1) {
    size_t need = (size_t)cand * 655360 + wbuf_end + 196608;
    if (need <= ws_size) { C = cand; break; }
  }
  unsigned short* base = (unsigned short*)((char*)d_ws + wbuf_end);
  unsigned short* Z0buf[2] = {base, base + (size_t)C * 65536};
  unsigned short* Z1buf[2] = {base + (size_t)2 * C * 65536, base + (size_t)3 * C * 65536};
  unsigned short* ys0buf[2] = {base + (size_t)4 * C * 65536,
                               base + (size_t)4 * C * 65536 + (size_t)C * 16384};
  unsigned short* ys1buf[2] = {base + (size_t)4 * C * 65536 + (size_t)2 * C * 16384,
                               base + (size_t)4 * C * 65536 + (size_t)3 * C * 16384};
  float* c0 = (float*)(base + (size_t)4 * C * 65536 + (size_t)4 * C * 16384);
  float* c1 = c0 + 16384;
  unsigned short* h0 = (unsigned short*)(c1 + 16384);
  unsigned short* h1 = h0 + 16384;

  const unsigned short* wih0f = wbuf + woff[0];
  const unsigned short* whh0f = wbuf + woff[1];
  const unsigned short* b0f   = wbuf + woff[2];
  const unsigned short* wih0b = wbuf + woff[3];
  const unsigned short* whh0b = wbuf + woff[4];
  const unsigned short* b0b   = wbuf + woff[5];
  const unsigned short* wih1f = wbuf + woff[6];
  const unsigned short* whh1f = wbuf + woff[7];
  const unsigned short* b1f   = wbuf + woff[8];
  const unsigned short* wih1b = wbuf + woff[9];
  const unsigned short* whh1b = wbuf + woff[10];
  const unsigned short* b1b   = wbuf + woff[11];
  const unsigned short* fcw   = wbuf + woff[12];
  const unsigned short* fcb   = wbuf + woff[13];

  detect_kernel<<<1, 256, 0, stream>>>((const unsigned short*)d_in[1], 49152, flag);
  convertw_kernel<<<614, 256, 0, stream>>>(
      d_in[1], d_in[2], d_in[3], d_in[4], d_in[5], d_in[6], d_in[7],
      d_in[8], d_in[9], d_in[10], d_in[11], d_in[12], d_in[13], d_in[14],
      wbuf, flag);

  const int nc = S / C;
  // prologue: gemm96 for chunk 0
  g96_kernel<<<C * 2, 512, 0, stream>>>(d_in[0], 0, flag,
                                        wih0f, wih0b, b0f, b0b, Z0buf[0]);

  const int GX = 64 + 4 * C + (C + 1) / 2;
  for (int c = 0; c <= nc + 1; ++c) {
    const int p = c & 1, pn = (c + 1) & 1;  // pn == (c-1)&1 == (c+1)&1
    rec_kernel<<<GX, 512, 0, stream>>>(
        // ctx a: L0 chunk c
        Z0buf[p], whh0f, whh0b, ys0buf[p], c0, h0, (c == 0) ? 1 : 0,
        (c <= nc - 1) ? 1 : 0,
        // ctx b: L1 chunk c-2
        Z1buf[p], whh1f, whh1b, ys1buf[p], c1, h1, (c == 2) ? 1 : 0,
        (c >= 2) ? 1 : 0,
        C,
        // embedded g96: chunk c+1
        d_in[0], (size_t)(c + 1) * C * 6144, (c <= nc - 2) ? 1 : 0, flag,
        wih0f, wih0b, b0f, b0b, Z0buf[pn],
        // embedded g256: chunk c-1 (ys0[(c-1)&1] -> Z1[(c-1)&1])
        ys0buf[pn], (c >= 1 && c <= nc) ? 1 : 0, wih1f, wih1b, b1f, b1b, Z1buf[pn],
        // embedded fc: chunk c-3 (reads ys1[(c-3)&1])
        ys1buf[pn], fcw, fcb, d_out,
        (c >= 3) ? (size_t)(c - 3) * C * 64 : 0, (c >= 3) ? C * 64 : 0);
  }
  // tail fc: chunk nc-1 (written during rec launch nc+1)
  fc_kernel<<<C * 16, 256, 0, stream>>>(ys1buf[(nc - 1) & 1], fcw, fcb, d_out,
                                        (size_t)(nc - 1) * C * 64, C * 64, flag);
}